// Round 8
// baseline (1319.967 us; speedup 1.0000x reference)
//
#include <hip/hip_runtime.h>
#include <cstdint>

#define F_H 200
#define F_W 200
#define D1  50176
#define NBOX 512
#define NHID 1024

typedef _Float16 f16;
typedef _Float16 half8 __attribute__((ext_vector_type(8)));
typedef _Float16 half4v __attribute__((ext_vector_type(4)));
typedef _Float16 half2v __attribute__((ext_vector_type(2)));
typedef float    f32x4 __attribute__((ext_vector_type(4)));

// ---------- helpers ----------
__device__ __forceinline__ void gload16(const void* g, void* l) {
  __builtin_amdgcn_global_load_lds((const __attribute__((address_space(1))) void*)g,
                                   (__attribute__((address_space(3))) void*)l,
                                   16, 0, 0);
}

__device__ __forceinline__ half2v pkrtz(float a, float b) {
  return __builtin_bit_cast(half2v, __builtin_amdgcn_cvt_pkrtz(a, b));
}

// f32 -> f16 hi + f16 lo*2^-11 split; flush sub-normal hi so result is identical
// regardless of MFMA input-denormal behavior.
__device__ __forceinline__ void splitf16(float v, f16& h, f16& l) {
  f16 hh = (f16)v;
  float hf = (float)hh;
  if (fabsf(hf) < 6.1035156e-5f) hf = 0.f;
  h = (f16)hh;
  if (fabsf(hf) < 6.1035156e-5f) h = (f16)0.f;
  l = (f16)((v - hf) * 2048.f);
}

// ---------- ROI align + split (2 outputs per thread, 4B stores) ----------
__global__ __launch_bounds__(256) void k_roi(const float* __restrict__ feat,
                                             const float* __restrict__ prop,
                                             f16* __restrict__ xhi, f16* __restrict__ xlo) {
  uint32_t idx = blockIdx.x * 256u + threadIdx.x;
  uint32_t n = idx / 25088u;
  uint32_t rem = idx % 25088u;
  uint32_t c = rem / 98u;
  uint32_t r2 = rem % 98u;
  uint32_t i = r2 / 7u;
  uint32_t jp = r2 % 7u;
  float b0 = prop[n * 4 + 0] * 0.25f, b1 = prop[n * 4 + 1] * 0.25f;
  float b2 = prop[n * 4 + 2] * 0.25f, b3 = prop[n * 4 + 3] * 0.25f;
  float ty = ((float)i + 0.5f) * (1.0f / 14.0f);
  float yy = b1 + (b3 - b1) * ty;
  float y0f = floorf(yy);
  float fy = yy - y0f;
  int y0 = (int)y0f; y0 = y0 < 0 ? 0 : (y0 > F_H - 1 ? F_H - 1 : y0);
  int y1 = y0 + 1 > F_H - 1 ? F_H - 1 : y0 + 1;
  const float* fr0 = feat + (size_t)c * (F_H * F_W) + (size_t)y0 * F_W;
  const float* fr1 = feat + (size_t)c * (F_H * F_W) + (size_t)y1 * F_W;
  f16 hs[2], ls[2];
#pragma unroll
  for (int e = 0; e < 2; ++e) {
    uint32_t j = jp * 2u + (uint32_t)e;
    float tx = ((float)j + 0.5f) * (1.0f / 14.0f);
    float xx = b0 + (b2 - b0) * tx;
    float x0f = floorf(xx);
    float fx = xx - x0f;
    int x0 = (int)x0f; x0 = x0 < 0 ? 0 : (x0 > F_W - 1 ? F_W - 1 : x0);
    int x1 = x0 + 1 > F_W - 1 ? F_W - 1 : x0 + 1;
    float v00 = fr0[x0], v01 = fr0[x1], v10 = fr1[x0], v11 = fr1[x1];
    float v = (1.f - fx) * (1.f - fy) * v00 + fx * (1.f - fy) * v01 +
              (1.f - fx) * fy * v10 + fx * fy * v11;
    splitf16(v, hs[e], ls[e]);
  }
  uint32_t base = n * 50176u + c * 196u + i * 14u + jp * 2u;
  half2v hv; hv[0] = hs[0]; hv[1] = hs[1];
  half2v lv; lv[0] = ls[0]; lv[1] = ls[1];
  *(half2v*)(xhi + base) = hv;
  *(half2v*)(xlo + base) = lv;
}

// ---------- transpose + split: W[K][N] f32 -> hiT/loT [N][K] f16 (64x64 LDS tiles) ----------
__global__ __launch_bounds__(256) void k_tsplit(const float* __restrict__ W,
                                                f16* __restrict__ hiT, f16* __restrict__ loT,
                                                int Kdim, int Ndim) {
  __shared__ f16 lh[64 * 72];
  __shared__ f16 ll[64 * 72];
  int t = threadIdx.x;
  int k0 = blockIdx.x * 64, n0 = blockIdx.y * 64;
  int r = t >> 2, cq = t & 3;
  const float* src = W + (size_t)(k0 + r) * Ndim + n0 + cq * 16;
  f16 hv[16], lv[16];
#pragma unroll
  for (int e = 0; e < 4; ++e) {
    f32x4 v = *(const f32x4*)(src + e * 4);
#pragma unroll
    for (int x = 0; x < 4; ++x) splitf16(v[x], hv[e * 4 + x], lv[e * 4 + x]);
  }
#pragma unroll
  for (int j = 0; j < 16; ++j) {
    int n_l = cq * 16 + j;
    lh[n_l * 72 + r] = hv[j];
    ll[n_l * 72 + r] = lv[j];
  }
  __syncthreads();
  f16* oh = hiT + (size_t)(n0 + r) * Kdim + k0 + cq * 16;
  f16* ol = loT + (size_t)(n0 + r) * Kdim + k0 + cq * 16;
  *(half8*)(oh)     = *(const half8*)(&lh[r * 72 + cq * 16]);
  *(half8*)(oh + 8) = *(const half8*)(&lh[r * 72 + cq * 16 + 8]);
  *(half8*)(ol)     = *(const half8*)(&ll[r * 72 + cq * 16]);
  *(half8*)(ol + 8) = *(const half8*)(&ll[r * 72 + cq * 16 + 8]);
}

// ---------- pack heads transposed+split: whT[n][k] planes + bias ----------
__global__ __launch_bounds__(256) void k_packT(const float* __restrict__ wc_, const float* __restrict__ bc,
                                               const float* __restrict__ wr_, const float* __restrict__ br,
                                               f16* __restrict__ whT_hi, f16* __restrict__ whT_lo,
                                               float* __restrict__ bh) {
  uint32_t idx = blockIdx.x * 256u + threadIdx.x;
  if (idx < 512u * 1024u) {
    uint32_t n = idx >> 10, k = idx & 1023u;
    float v = 0.f;
    if (n < 81u) v = wc_[k * 81u + n];
    else if (n < 405u) v = wr_[k * 324u + (n - 81u)];
    f16 h, l; splitf16(v, h, l);
    whT_hi[idx] = h; whT_lo[idx] = l;
  } else if (idx < 512u * 1024u + 512u) {
    uint32_t n = idx - 512u * 1024u;
    float v = 0.f;
    if (n < 81u) v = bc[n];
    else if (n < 405u) v = br[n - 81u];
    bh[n] = v;
  }
}

// ---------- symmetric split-f16 GEMM: A[M][K], B-T [N][K] planes, 256x256, BK=32 ----------
// (used for FC2 and heads; proven passing since R4)
__global__ __launch_bounds__(512, 2) void k_gemm2(
    const f16* __restrict__ Ahi, const f16* __restrict__ Alo,
    const f16* __restrict__ Bhi, const f16* __restrict__ Blo,
    float* __restrict__ Cp, int K, int N, int Kc, int nMt, int nNt)
{
  __shared__ char sm[131072];
  const int t = threadIdx.x;
  const int lane = t & 63;
  const int wid = t >> 6;
  const int wr = wid >> 2;
  const int wc = wid & 3;
  const int rl = lane & 15;
  const int lq = lane >> 4;

  int bid = blockIdx.x;
  int low = bid & 7, qq = bid >> 3;
  int nt = qq % nNt;
  int chi = qq / nNt;
  int c = chi * 8 + low;
  int ks = c / nMt;
  int mt = c % nMt;
  const int brow = mt * 256;
  const int nbase = nt * 256;
  const int k0 = ks * Kc;
  const int nk = Kc >> 5;

  uint32_t aoffg[2], aldso[2];
#pragma unroll
  for (int i = 0; i < 2; ++i) {
    uint32_t idx = (uint32_t)t + 512u * i;
    uint32_t q2 = idx >> 2, s = idx & 3;
    uint32_t qh = q2 >> 6;
    uint32_t grh = (qh == 1u) ? 2u : (qh == 2u) ? 1u : qh;
    uint32_t gr = grh * 64u + (q2 & 63u);
    aoffg[i] = (uint32_t)(brow + gr) * (uint32_t)K + (s ^ ((q2 >> 1) & 3u)) * 8u;
    aldso[i] = idx * 16u;
  }
  uint32_t boffg[2], bldso[2];
#pragma unroll
  for (int i = 0; i < 2; ++i) {
    uint32_t idx = (uint32_t)t + 512u * i;
    uint32_t rB = idx >> 2, s = idx & 3;
    boffg[i] = (uint32_t)(nbase + rB) * (uint32_t)K + (s ^ ((rB >> 1) & 3u)) * 8u;
    bldso[i] = idx * 16u;
  }

  const uint32_t swzk = (uint32_t)(lq ^ ((rl >> 1) & 3)) * 16u;
  const uint32_t a_off_lane = (uint32_t)(rl * 64) + swzk;
  const uint32_t b_off_lane = (uint32_t)((wc * 16 + rl) * 64) + swzk;

  f32x4 zero4 = {0.f, 0.f, 0.f, 0.f};
  f32x4 acc[8][4];
#pragma unroll
  for (int m = 0; m < 8; ++m)
#pragma unroll
    for (int n = 0; n < 4; ++n) acc[m][n] = zero4;

#define PH0STAGE(LB, KB) do { \
    gload16(Bhi + boffg[0] + (KB), (LB) + 32768 + bldso[0]); \
    gload16(Blo + boffg[0] + (KB), (LB) + 49152 + bldso[0]); \
    gload16(Bhi + boffg[1] + (KB), (LB) + 32768 + bldso[1]); \
    gload16(Blo + boffg[1] + (KB), (LB) + 49152 + bldso[1]); \
    gload16(Ahi + aoffg[0] + (KB), (LB) + aldso[0]); \
    gload16(Alo + aoffg[0] + (KB), (LB) + 16384 + aldso[0]); \
  } while (0)

#define PH1STAGE(LB, KB) do { \
    gload16(Ahi + aoffg[1] + (KB), (LB) + aldso[1]); \
    gload16(Alo + aoffg[1] + (KB), (LB) + 16384 + aldso[1]); \
  } while (0)

#define COMPUTE_PHASE(P) do { \
    half8 bh2[4], bl2[4]; \
    _Pragma("unroll") \
    for (int nf = 0; nf < 4; ++nf) { \
      bh2[nf] = *(const half8*)(lb + 32768 + nf * 4096 + b_off_lane); \
      bl2[nf] = *(const half8*)(lb + 49152 + nf * 4096 + b_off_lane); \
    } \
    __builtin_amdgcn_s_setprio(1); \
    _Pragma("unroll") \
    for (int mm = 0; mm < 4; ++mm) { \
      const char* ab = lb + (P) * 8192 + wr * 4096 + mm * 1024 + a_off_lane; \
      half8 ah = *(const half8*)(ab); \
      half8 al = *(const half8*)(ab + 16384); \
      _Pragma("unroll") \
      for (int nf = 0; nf < 4; ++nf) { \
        acc[(P)*4+mm][nf] = __builtin_amdgcn_mfma_f32_16x16x32_f16(ah, bh2[nf], acc[(P)*4+mm][nf], 0, 0, 0); \
        f32x4 tt = __builtin_amdgcn_mfma_f32_16x16x32_f16(ah, bl2[nf], zero4, 0, 0, 0); \
        tt = __builtin_amdgcn_mfma_f32_16x16x32_f16(al, bh2[nf], tt, 0, 0, 0); \
        acc[(P)*4+mm][nf] += tt * 4.8828125e-4f; \
      } \
    } \
    __builtin_amdgcn_s_setprio(0); \
  } while (0)

  PH0STAGE(sm, (uint32_t)k0);
  PH1STAGE(sm, (uint32_t)k0);

  int cur = 0;
  for (int kt = 0; kt < nk; ++kt) {
    int ktn = (kt + 1 < nk) ? kt + 1 : kt;
    uint32_t kbn = (uint32_t)(k0 + ktn * 32);
    const char* lb = sm + cur * 65536;
    char* lbn = sm + (cur ^ 1) * 65536;

    asm volatile("s_waitcnt vmcnt(2)" ::: "memory");
    __builtin_amdgcn_s_barrier();
    __builtin_amdgcn_sched_barrier(0);
    PH0STAGE(lbn, kbn);
    COMPUTE_PHASE(0);

    asm volatile("s_waitcnt vmcnt(6)" ::: "memory");
    __builtin_amdgcn_s_barrier();
    __builtin_amdgcn_sched_barrier(0);
    PH1STAGE(lbn, kbn);
    COMPUTE_PHASE(1);

    cur ^= 1;
  }

  float* Cs = Cp + (size_t)ks * ((size_t)512 * (uint32_t)N);
#pragma unroll
  for (int m = 0; m < 8; ++m) {
    int rg = brow + wr * 128 + m * 16 + lq * 4;
#pragma unroll
    for (int nf = 0; nf < 4; ++nf) {
      int cg = nbase + nf * 64 + wc * 16 + rl;
#pragma unroll
      for (int rr = 0; rr < 4; ++rr)
        Cs[(size_t)(rg + rr) * (uint32_t)N + cg] = acc[m][nf][rr];
    }
  }
#undef PH0STAGE
#undef PH1STAGE
}

// ---------- FC1 GEMM: producer/consumer wave specialization, 768 threads ----------
// Waves 0-7 (512 thr): consumers — pure ds_read + MFMA + fold, one barrier/step.
// Waves 8-11 (256 thr): producers — all B f32 loads + split + ds_write, A gload_lds.
// Per-wave vmcnt: producers run counted pipeline {vmcnt(8) B(t+1) -> WRITEB ;
// vmcnt(32) A(t+1) landed, B(t+2) in flight}. Consumers never touch VMEM.
__global__ __launch_bounds__(768, 1) void k_gemm3(
    const f16* __restrict__ Ahi, const f16* __restrict__ Alo,
    const float* __restrict__ B, float* __restrict__ Cp,
    int K, int N, int Kc, int nMt, int nNt)
{
  __shared__ char sm[131072];
  const int t = threadIdx.x;
  const int lane = t & 63;
  const int wid = t >> 6;
  const bool isProd = (t >= 512);
  const int wr = (wid >> 2) & 1;
  const int wc = wid & 3;
  const int rl = lane & 15;
  const int lq = lane >> 4;

  int bid = blockIdx.x;
  int low = bid & 7, qq = bid >> 3;
  int nt = qq % nNt;
  int chi = qq / nNt;
  int c = chi * 8 + low;
  int ks = c / nMt;
  int mt = c % nMt;
  const int brow = mt * 256;
  const int nbase = nt * 256;
  const int k0 = ks * Kc;
  const int nk = Kc >> 5;

  // ---- producer constants (valid for t>=512; tp in [0,256)) ----
  const int tp = t & 255;
  // A staging: 8 gload16 per producer thread (4 per plane), same layout recipe as k_gemm2
  uint32_t aoffg[4], aldso[4];
#pragma unroll
  for (int i = 0; i < 4; ++i) {
    uint32_t idx = (uint32_t)tp + 256u * i;   // 0..1023 segs per plane
    uint32_t q2 = idx >> 2, s = idx & 3;
    uint32_t qh = q2 >> 6;
    uint32_t grh = (qh == 1u) ? 2u : (qh == 2u) ? 1u : qh;
    uint32_t gr = grh * 64u + (q2 & 63u);
    aoffg[i] = (uint32_t)(brow + gr) * (uint32_t)K + (s ^ ((q2 >> 1) & 3u)) * 8u;
    aldso[i] = idx * 16u;
  }
  // B: producer thread owns n-row tp, all 32 k's of the step
  const float* bsrc0 = B + (size_t)(uint32_t)k0 * (uint32_t)N + (uint32_t)nbase + (uint32_t)tp;
  const uint32_t bswz = ((uint32_t)tp >> 1) & 3u;
  uint32_t wbseg[4];
#pragma unroll
  for (int s2 = 0; s2 < 4; ++s2)
    wbseg[s2] = (uint32_t)tp * 64u + ((((uint32_t)s2) ^ bswz) << 4);

  // ---- consumer constants ----
  const uint32_t swzk = (uint32_t)(lq ^ ((rl >> 1) & 3)) * 16u;
  const uint32_t a_off_lane = (uint32_t)(rl * 64) + swzk;
  const uint32_t b_off_lane = (uint32_t)((wc * 16 + rl) * 64) + swzk;

  f32x4 zero4 = {0.f, 0.f, 0.f, 0.f};
  f32x4 acc[8][4];
#pragma unroll
  for (int m = 0; m < 8; ++m)
#pragma unroll
    for (int n = 0; n < 4; ++n) acc[m][n] = zero4;

  float bxr[32], byr[32];                      // producer B register double-buffer

#define LOADB(ARR, KT) do { \
    _Pragma("unroll") \
    for (int j = 0; j < 32; ++j) \
      ARR[j] = bsrc0[(size_t)((uint32_t)(KT) * 32u + (uint32_t)j) * (uint32_t)N]; \
  } while (0)

#define WRITEB(LB, ARR) do { \
    _Pragma("unroll") \
    for (int s2 = 0; s2 < 4; ++s2) { \
      half8 h8, l8; \
      _Pragma("unroll") \
      for (int j = 0; j < 8; j += 2) { \
        float v0 = ARR[s2 * 8 + j], v1 = ARR[s2 * 8 + j + 1]; \
        half2v hp = pkrtz(v0, v1); \
        f16 e0 = (fabsf(v0) >= 6.1035156e-5f) ? hp[0] : (f16)0; \
        f16 e1 = (fabsf(v1) >= 6.1035156e-5f) ? hp[1] : (f16)0; \
        half2v lp = pkrtz((v0 - (float)e0) * 2048.f, (v1 - (float)e1) * 2048.f); \
        h8[j] = e0; h8[j + 1] = e1; l8[j] = lp[0]; l8[j + 1] = lp[1]; \
      } \
      *(half8*)((LB) + 32768 + wbseg[s2]) = h8; \
      *(half8*)((LB) + 49152 + wbseg[s2]) = l8; \
    } \
  } while (0)

#define STAGE_A8(LB, KB) do { \
    _Pragma("unroll") \
    for (int i = 0; i < 4; ++i) { \
      gload16(Ahi + aoffg[i] + (KB), (LB) + aldso[i]); \
      gload16(Alo + aoffg[i] + (KB), (LB) + 16384 + aldso[i]); \
    } \
  } while (0)

#define COMPUTE_PHASE(P) do { \
    half8 bh2[4], bl2[4]; \
    _Pragma("unroll") \
    for (int nf = 0; nf < 4; ++nf) { \
      bh2[nf] = *(const half8*)(lb + 32768 + nf * 4096 + b_off_lane); \
      bl2[nf] = *(const half8*)(lb + 49152 + nf * 4096 + b_off_lane); \
    } \
    __builtin_amdgcn_s_setprio(1); \
    _Pragma("unroll") \
    for (int mm = 0; mm < 4; ++mm) { \
      const char* ab = lb + (P) * 8192 + wr * 4096 + mm * 1024 + a_off_lane; \
      half8 ah = *(const half8*)(ab); \
      half8 al = *(const half8*)(ab + 16384); \
      _Pragma("unroll") \
      for (int nf = 0; nf < 4; ++nf) { \
        acc[(P)*4+mm][nf] = __builtin_amdgcn_mfma_f32_16x16x32_f16(ah, bh2[nf], acc[(P)*4+mm][nf], 0, 0, 0); \
        f32x4 tt = __builtin_amdgcn_mfma_f32_16x16x32_f16(ah, bl2[nf], zero4, 0, 0, 0); \
        tt = __builtin_amdgcn_mfma_f32_16x16x32_f16(al, bh2[nf], tt, 0, 0, 0); \
        acc[(P)*4+mm][nf] += tt * 4.8828125e-4f; \
      } \
    } \
    __builtin_amdgcn_s_setprio(0); \
  } while (0)

  // One K-step. Consumers compute tile KT from buf cur; producers fill buf cur^1
  // with tile KT+1 (A via gload_lds, B via regs IN) and load B(KT+2) into OUT.
#define ITER(KT, IN, OUT) do { \
    int kA = ((KT) + 1 < nk) ? (KT) + 1 : nk - 1; \
    int kB = ((KT) + 2 < nk) ? (KT) + 2 : nk - 1; \
    const char* lb = sm + cur * 65536; \
    char* lbn = sm + (cur ^ 1) * 65536; \
    if (isProd) { \
      STAGE_A8(lbn, (uint32_t)(k0 + kA * 32));            /* out: B32(IN)+A8 = 40 */ \
      asm volatile("s_waitcnt vmcnt(8)" ::: "memory");    /* B(KT+1) regs landed */ \
      __builtin_amdgcn_sched_barrier(0); \
      WRITEB(lbn, IN); \
      LOADB(OUT, kB);                                     /* out: A8+B32 = 40 */ \
      asm volatile("s_waitcnt vmcnt(32) lgkmcnt(0)" ::: "memory");  /* A landed */ \
      __builtin_amdgcn_sched_barrier(0); \
    } else { \
      COMPUTE_PHASE(0); \
      COMPUTE_PHASE(1); \
      asm volatile("s_waitcnt lgkmcnt(0)" ::: "memory"); \
      __builtin_amdgcn_sched_barrier(0); \
    } \
    __builtin_amdgcn_s_barrier(); \
    cur ^= 1; \
  } while (0)

  // prologue: producers fill buf0 with tile 0, preload B(1) regs
  if (isProd) {
    LOADB(bxr, 0);                              // VM 32
    STAGE_A8(sm, (uint32_t)k0);                 // VM 40
    asm volatile("s_waitcnt vmcnt(8)" ::: "memory");   // B(0) landed
    __builtin_amdgcn_sched_barrier(0);
    WRITEB(sm, bxr);
    LOADB(byr, (nk > 1) ? 1 : 0);               // VM 40 (byr = B(1))
    asm volatile("s_waitcnt vmcnt(32) lgkmcnt(0)" ::: "memory");  // A(0) landed
    __builtin_amdgcn_sched_barrier(0);
  }
  __builtin_amdgcn_s_barrier();

  int cur = 0;
  int kt = 0;
  for (; kt + 1 < nk; kt += 2) {
    ITER(kt, byr, bxr);
    ITER(kt + 1, bxr, byr);
  }
  if (kt < nk) ITER(kt, byr, bxr);              // nk odd tail (IN=byr: correct parity)

  if (!isProd) {
    float* Cs = Cp + (size_t)ks * ((size_t)512 * (uint32_t)N);
#pragma unroll
    for (int m = 0; m < 8; ++m) {
      int rg = brow + wr * 128 + m * 16 + lq * 4;
#pragma unroll
      for (int nf = 0; nf < 4; ++nf) {
        int cg = nbase + nf * 64 + wc * 16 + rl;
#pragma unroll
        for (int rr = 0; rr < 4; ++rr)
          Cs[(size_t)(rg + rr) * (uint32_t)N + cg] = acc[m][nf][rr];
      }
    }
  }
#undef LOADB
#undef WRITEB
#undef STAGE_A8
#undef ITER
#undef COMPUTE_PHASE
}

// ---------- reduce split-K partials (+bias, relu), float4 vectorized ----------
__global__ __launch_bounds__(256) void k_reduce(
    const float* __restrict__ parts, const float* __restrict__ bias,
    int nS, int MN4, int Ncols, int relu,
    float* __restrict__ outf, f16* __restrict__ ohi, f16* __restrict__ olo)
{
  uint32_t idx = blockIdx.x * 256u + threadIdx.x;
  if (idx >= (uint32_t)MN4) return;
  f32x4 s = *(const f32x4*)(bias + ((idx * 4u) % (uint32_t)Ncols));
  const f32x4* p4 = (const f32x4*)parts;
  for (int i = 0; i < nS; ++i) s += p4[(size_t)i * (uint32_t)MN4 + idx];
  if (relu) {
#pragma unroll
    for (int j = 0; j < 4; ++j) s[j] = fmaxf(s[j], 0.f);
  }
  if (outf) *(f32x4*)(outf + (size_t)idx * 4) = s;
  if (ohi) {
    half4v h, l;
#pragma unroll
    for (int j = 0; j < 4; ++j) { f16 hh, ll; splitf16(s[j], hh, ll); h[j] = hh; l[j] = ll; }
    *(half4v*)(ohi + (size_t)idx * 4) = h;
    *(half4v*)(olo + (size_t)idx * 4) = l;
  }
}

// ---------- per-row softmax / label / score / box decode ----------
__global__ __launch_bounds__(256) void k_post(
    const float* __restrict__ ld, const float* __restrict__ prop,
    float* __restrict__ boxes, float* __restrict__ scores, int* __restrict__ labels)
{
  int n = blockIdx.x * 256 + threadIdx.x;
  if (n >= NBOX) return;
  const float* L = ld + (size_t)n * 512;
  float m = L[0];
  for (int j = 1; j < 81; ++j) m = fmaxf(m, L[j]);
  float sum = 0.f;
  for (int j = 0; j < 81; ++j) sum += expf(L[j] - m);
  float best = -1.f; int bj = 1;
  for (int j = 1; j < 81; ++j) {
    float p = expf(L[j] - m) / sum;
    if (p > best) { best = p; bj = j; }
  }
  float d0 = L[81 + bj * 4 + 0];
  float d1 = L[81 + bj * 4 + 1];
  float d2 = L[81 + bj * 4 + 2];
  float d3 = L[81 + bj * 4 + 3];
  float p0 = prop[n * 4 + 0], p1 = prop[n * 4 + 1], p2 = prop[n * 4 + 2], p3 = prop[n * 4 + 3];
  float w = p2 - p0, h = p3 - p1;
  float cx = p0 + 0.5f * w, cy = p1 + 0.5f * h;
  float px = cx + d0 * w, py = cy + d1 * h;
  float pw = w * expf(fminf(fmaxf(d2, -4.f), 4.f));
  float ph = h * expf(fminf(fmaxf(d3, -4.f), 4.f));
  float bx0 = px - 0.5f * pw, by0 = py - 0.5f * ph;
  float bx1 = px + 0.5f * pw, by1 = py + 0.5f * ph;
  boxes[n * 4 + 0] = fminf(fmaxf(bx0, 0.f), 799.f);
  boxes[n * 4 + 1] = fminf(fmaxf(by0, 0.f), 799.f);
  boxes[n * 4 + 2] = fminf(fmaxf(bx1, 0.f), 799.f);
  boxes[n * 4 + 3] = fminf(fmaxf(by1, 0.f), 799.f);
  scores[n] = best;
  labels[n] = bj;
}

// ---------- stable descending bitonic sort ----------
__global__ __launch_bounds__(512) void k_sort(
    const float* __restrict__ scores, const float* __restrict__ boxes, const int* __restrict__ labels,
    float* __restrict__ bs, float* __restrict__ ss, int* __restrict__ ls)
{
  __shared__ unsigned long long keys[512];
  int t = threadIdx.x;
  unsigned sb = __float_as_uint(scores[t]);
  keys[t] = ((unsigned long long)(0xFFFFFFFFu - sb) << 32) | (unsigned)t;
  __syncthreads();
  for (int k = 2; k <= 512; k <<= 1) {
    for (int j = k >> 1; j > 0; j >>= 1) {
      int p = t ^ j;
      if (p > t) {
        unsigned long long a = keys[t], b = keys[p];
        bool asc = ((t & k) == 0);
        if (asc ? (a > b) : (a < b)) { keys[t] = b; keys[p] = a; }
      }
      __syncthreads();
    }
  }
  unsigned o = (unsigned)(keys[t] & 0xFFFFFFFFu);
  ss[t] = scores[o];
  ls[t] = labels[o];
  bs[t * 4 + 0] = boxes[o * 4 + 0];
  bs[t * 4 + 1] = boxes[o * 4 + 1];
  bs[t * 4 + 2] = boxes[o * 4 + 2];
  bs[t * 4 + 3] = boxes[o * 4 + 3];
}

// ---------- IoU suppression bitmask ----------
__global__ __launch_bounds__(64) void k_mask(const float* __restrict__ bs,
                                             unsigned long long* __restrict__ mask) {
  int i = blockIdx.x;
  int lane = threadIdx.x;
  float ax0 = bs[i * 4], ay0 = bs[i * 4 + 1], ax1 = bs[i * 4 + 2], ay1 = bs[i * 4 + 3];
  float aarea = fmaxf(ax1 - ax0, 0.f) * fmaxf(ay1 - ay0, 0.f);
  for (int w = 0; w < 8; ++w) {
    int j = w * 64 + lane;
    float bx0 = bs[j * 4], by0 = bs[j * 4 + 1], bx1 = bs[j * 4 + 2], by1 = bs[j * 4 + 3];
    float barea = fmaxf(bx1 - bx0, 0.f) * fmaxf(by1 - by0, 0.f);
    float ix0 = fmaxf(ax0, bx0), iy0 = fmaxf(ay0, by0);
    float ix1 = fminf(ax1, bx1), iy1 = fminf(ay1, by1);
    float inter = fmaxf(ix1 - ix0, 0.f) * fmaxf(iy1 - iy0, 0.f);
    float iou = inter / (aarea + barea - inter + 1e-6f);
    bool cond = (iou > 0.5f) && (j > i);
    unsigned long long b = __ballot(cond);
    if (lane == 0) mask[i * 8 + w] = b;
  }
}

// ---------- sequential NMS + output assembly ----------
__global__ __launch_bounds__(64) void k_nms(const unsigned long long* __restrict__ mask,
                                            const float* __restrict__ ss,
                                            const float* __restrict__ bs,
                                            const int* __restrict__ ls,
                                            float* __restrict__ out) {
  int lane = threadIdx.x;
  unsigned long long bal[8];
  for (int w = 0; w < 8; ++w) bal[w] = __ballot(ss[w * 64 + lane] > 0.05f);
  unsigned long long keep = (lane < 8) ? bal[lane] : 0ULL;
  for (int i = 0; i < 512; ++i) {
    unsigned long long kw = __shfl(keep, i >> 6);
    if ((kw >> (i & 63)) & 1ULL) {
      unsigned long long mi = (lane < 8) ? mask[i * 8 + lane] : 0ULL;
      keep &= ~mi;
    }
  }
  __shared__ unsigned long long kws[8];
  if (lane < 8) kws[lane] = keep;
  __syncthreads();
  for (int it = 0; it < 56; ++it) {
    int idx = lane + it * 64;
    float val;
    if (idx < 2560) {
      int i = idx / 5, c2 = idx % 5;
      bool kb = (kws[i >> 6] >> (i & 63)) & 1ULL;
      val = kb ? (c2 < 4 ? bs[i * 4 + c2] : ss[i]) : 0.f;
    } else if (idx < 3072) {
      int i = idx - 2560;
      val = (float)ls[i];
    } else {
      int i = idx - 3072;
      val = ((kws[i >> 6] >> (i & 63)) & 1ULL) ? 1.f : 0.f;
    }
    out[idx] = val;
  }
}

// ---------- workspace layout ----------
static constexpr size_t SZ_X    = (size_t)NBOX * D1 * 2;            // 51,380,224
static constexpr size_t SZ_PART = (size_t)32 * 512 * 1024 * 4;      // 67,108,864
static constexpr size_t SZ_H    = (size_t)512 * 1024 * 2;
static constexpr size_t NP_XHI   = 0;
static constexpr size_t NP_XLO   = NP_XHI + SZ_X;
static constexpr size_t NP_PART  = NP_XLO + SZ_X;
static constexpr size_t NP_W2HIT = NP_PART + SZ_PART;
static constexpr size_t NP_W2LOT = NP_W2HIT + (size_t)1024 * 1024 * 2;
static constexpr size_t NP_WHHIT = NP_W2LOT + (size_t)1024 * 1024 * 2;
static constexpr size_t NP_WHLOT = NP_WHHIT + (size_t)512 * 1024 * 2;
static constexpr size_t NP_BH    = NP_WHLOT + (size_t)512 * 1024 * 2;
static constexpr size_t NP_H1HI  = NP_BH + 4096;
static constexpr size_t NP_H1LO  = NP_H1HI + SZ_H;
static constexpr size_t NP_H2HI  = NP_H1LO + SZ_H;
static constexpr size_t NP_H2LO  = NP_H2HI + SZ_H;
static constexpr size_t NP_LD    = NP_H2LO + SZ_H;
static constexpr size_t NP_BOX   = NP_LD + (size_t)512 * 512 * 4;
static constexpr size_t NP_SC    = NP_BOX + 512 * 4 * 4;
static constexpr size_t NP_LB    = NP_SC + 4096;
static constexpr size_t NP_BS    = NP_LB + 4096;
static constexpr size_t NP_SS    = NP_BS + 512 * 4 * 4;
static constexpr size_t NP_LS    = NP_SS + 4096;
static constexpr size_t NP_MASK  = NP_LS + 4096;
static constexpr size_t NP_END   = NP_MASK + (size_t)512 * 8 * 8;

extern "C" void kernel_launch(void* const* d_in, const int* in_sizes, int n_in,
                              void* d_out, int out_size, void* d_ws, size_t ws_size,
                              hipStream_t stream)
{
  (void)in_sizes; (void)n_in;
  const float* feat = (const float*)d_in[0];
  const float* prop = (const float*)d_in[1];
  const float* w1   = (const float*)d_in[2];
  const float* b1   = (const float*)d_in[3];
  const float* w2   = (const float*)d_in[4];
  const float* b2   = (const float*)d_in[5];
  const float* wcls = (const float*)d_in[6];
  const float* bcls = (const float*)d_in[7];
  const float* wreg = (const float*)d_in[8];
  const float* breg = (const float*)d_in[9];
  float* out = (float*)d_out;
  char* W = (char*)d_ws;

  if (ws_size < NP_END) {                      // sentinel: workspace too small
    (void)hipMemsetAsync(out, 0x7f, (size_t)out_size * 4, stream);
    return;
  }

  f16*   xhi   = (f16*)(W + NP_XHI);
  f16*   xlo   = (f16*)(W + NP_XLO);
  float* parts = (float*)(W + NP_PART);
  f16*   w2hiT = (f16*)(W + NP_W2HIT);
  f16*   w2loT = (f16*)(W + NP_W2LOT);
  f16*   whHiT = (f16*)(W + NP_WHHIT);
  f16*   whLoT = (f16*)(W + NP_WHLOT);
  float* bhead = (float*)(W + NP_BH);
  f16*   h1hi  = (f16*)(W + NP_H1HI);
  f16*   h1lo  = (f16*)(W + NP_H1LO);
  f16*   h2hi  = (f16*)(W + NP_H2HI);
  f16*   h2lo  = (f16*)(W + NP_H2LO);
  float* ldbuf = (float*)(W + NP_LD);
  float* boxes = (float*)(W + NP_BOX);
  float* scores= (float*)(W + NP_SC);
  int*   labels= (int*)(W + NP_LB);
  float* bsrt  = (float*)(W + NP_BS);
  float* ssrt  = (float*)(W + NP_SS);
  int*   lsrt  = (int*)(W + NP_LS);
  unsigned long long* maskb = (unsigned long long*)(W + NP_MASK);

  k_roi<<<50176, 256, 0, stream>>>(feat, prop, xhi, xlo);
  k_tsplit<<<dim3(1024 / 64, 1024 / 64), 256, 0, stream>>>(w2, w2hiT, w2loT, 1024, 1024);
  k_packT<<<2050, 256, 0, stream>>>(wcls, bcls, wreg, breg, whHiT, whLoT, bhead);

  // FC1: M=512 N=1024 K=50176, Kc=1568, grid 2*4*32=256, producer/consumer
  k_gemm3<<<256, 768, 0, stream>>>(xhi, xlo, w1, parts, D1, 1024, 1568, 2, 4);
  k_reduce<<<512, 256, 0, stream>>>(parts, b1, 32, 131072, 1024, 1, nullptr, h1hi, h1lo);

  // FC2: K=1024, Kc=32, grid 2*4*32=256
  k_gemm2<<<256, 512, 0, stream>>>(h1hi, h1lo, w2hiT, w2loT, parts, 1024, 1024, 32, 2, 4);
  k_reduce<<<512, 256, 0, stream>>>(parts, b2, 32, 131072, 1024, 1, nullptr, h2hi, h2lo);

  // heads: N=512, Kc=32, grid 2*2*32=128
  k_gemm2<<<128, 512, 0, stream>>>(h2hi, h2lo, whHiT, whLoT, parts, 1024, 512, 32, 2, 2);
  k_reduce<<<256, 256, 0, stream>>>(parts, bhead, 32, 65536, 512, 0, ldbuf, nullptr, nullptr);

  k_post<<<2, 256, 0, stream>>>(ldbuf, prop, boxes, scores, labels);
  k_sort<<<1, 512, 0, stream>>>(scores, boxes, labels, bsrt, ssrt, lsrt);
  k_mask<<<512, 64, 0, stream>>>(bsrt, maskb);
  k_nms<<<1, 64, 0, stream>>>(maskb, ssrt, bsrt, lsrt, out);
}

// Round 9
// 483.235 us; speedup vs baseline: 2.7315x; 2.7315x over previous
//
#include <hip/hip_runtime.h>
#include <cstdint>

#define F_H 200
#define F_W 200
#define D1  50176
#define NBOX 512
#define NHID 1024

typedef _Float16 f16;
typedef _Float16 half8 __attribute__((ext_vector_type(8)));
typedef _Float16 half4v __attribute__((ext_vector_type(4)));
typedef _Float16 half2v __attribute__((ext_vector_type(2)));
typedef float    f32x4 __attribute__((ext_vector_type(4)));

// ---------- helpers ----------
__device__ __forceinline__ void gload16(const void* g, void* l) {
  __builtin_amdgcn_global_load_lds((const __attribute__((address_space(1))) void*)g,
                                   (__attribute__((address_space(3))) void*)l,
                                   16, 0, 0);
}

__device__ __forceinline__ half2v pkrtz(float a, float b) {
  return __builtin_bit_cast(half2v, __builtin_amdgcn_cvt_pkrtz(a, b));
}

// f32 -> f16 hi + f16 lo*2^-11 split; flush sub-normal hi so result is identical
// regardless of MFMA input-denormal behavior.
__device__ __forceinline__ void splitf16(float v, f16& h, f16& l) {
  f16 hh = (f16)v;
  float hf = (float)hh;
  if (fabsf(hf) < 6.1035156e-5f) hf = 0.f;
  h = (f16)hh;
  if (fabsf(hf) < 6.1035156e-5f) h = (f16)0.f;
  l = (f16)((v - hf) * 2048.f);
}

// ---------- ROI align + split (2 outputs per thread, 4B stores) ----------
__global__ __launch_bounds__(256) void k_roi(const float* __restrict__ feat,
                                             const float* __restrict__ prop,
                                             f16* __restrict__ xhi, f16* __restrict__ xlo) {
  uint32_t idx = blockIdx.x * 256u + threadIdx.x;
  uint32_t n = idx / 25088u;
  uint32_t rem = idx % 25088u;
  uint32_t c = rem / 98u;
  uint32_t r2 = rem % 98u;
  uint32_t i = r2 / 7u;
  uint32_t jp = r2 % 7u;
  float b0 = prop[n * 4 + 0] * 0.25f, b1 = prop[n * 4 + 1] * 0.25f;
  float b2 = prop[n * 4 + 2] * 0.25f, b3 = prop[n * 4 + 3] * 0.25f;
  float ty = ((float)i + 0.5f) * (1.0f / 14.0f);
  float yy = b1 + (b3 - b1) * ty;
  float y0f = floorf(yy);
  float fy = yy - y0f;
  int y0 = (int)y0f; y0 = y0 < 0 ? 0 : (y0 > F_H - 1 ? F_H - 1 : y0);
  int y1 = y0 + 1 > F_H - 1 ? F_H - 1 : y0 + 1;
  const float* fr0 = feat + (size_t)c * (F_H * F_W) + (size_t)y0 * F_W;
  const float* fr1 = feat + (size_t)c * (F_H * F_W) + (size_t)y1 * F_W;
  f16 hs[2], ls[2];
#pragma unroll
  for (int e = 0; e < 2; ++e) {
    uint32_t j = jp * 2u + (uint32_t)e;
    float tx = ((float)j + 0.5f) * (1.0f / 14.0f);
    float xx = b0 + (b2 - b0) * tx;
    float x0f = floorf(xx);
    float fx = xx - x0f;
    int x0 = (int)x0f; x0 = x0 < 0 ? 0 : (x0 > F_W - 1 ? F_W - 1 : x0);
    int x1 = x0 + 1 > F_W - 1 ? F_W - 1 : x0 + 1;
    float v00 = fr0[x0], v01 = fr0[x1], v10 = fr1[x0], v11 = fr1[x1];
    float v = (1.f - fx) * (1.f - fy) * v00 + fx * (1.f - fy) * v01 +
              (1.f - fx) * fy * v10 + fx * fy * v11;
    splitf16(v, hs[e], ls[e]);
  }
  uint32_t base = n * 50176u + c * 196u + i * 14u + jp * 2u;
  half2v hv; hv[0] = hs[0]; hv[1] = hs[1];
  half2v lv; lv[0] = ls[0]; lv[1] = ls[1];
  *(half2v*)(xhi + base) = hv;
  *(half2v*)(xlo + base) = lv;
}

// ---------- transpose + split: W[K][N] f32 -> hiT/loT [N][K] f16 (64x64 LDS tiles) ----------
__global__ __launch_bounds__(256) void k_tsplit(const float* __restrict__ W,
                                                f16* __restrict__ hiT, f16* __restrict__ loT,
                                                int Kdim, int Ndim) {
  __shared__ f16 lh[64 * 72];
  __shared__ f16 ll[64 * 72];
  int t = threadIdx.x;
  int k0 = blockIdx.x * 64, n0 = blockIdx.y * 64;
  int r = t >> 2, cq = t & 3;
  const float* src = W + (size_t)(k0 + r) * Ndim + n0 + cq * 16;
  f16 hv[16], lv[16];
#pragma unroll
  for (int e = 0; e < 4; ++e) {
    f32x4 v = *(const f32x4*)(src + e * 4);
#pragma unroll
    for (int x = 0; x < 4; ++x) splitf16(v[x], hv[e * 4 + x], lv[e * 4 + x]);
  }
#pragma unroll
  for (int j = 0; j < 16; ++j) {
    int n_l = cq * 16 + j;
    lh[n_l * 72 + r] = hv[j];
    ll[n_l * 72 + r] = lv[j];
  }
  __syncthreads();
  f16* oh = hiT + (size_t)(n0 + r) * Kdim + k0 + cq * 16;
  f16* ol = loT + (size_t)(n0 + r) * Kdim + k0 + cq * 16;
  *(half8*)(oh)     = *(const half8*)(&lh[r * 72 + cq * 16]);
  *(half8*)(oh + 8) = *(const half8*)(&lh[r * 72 + cq * 16 + 8]);
  *(half8*)(ol)     = *(const half8*)(&ll[r * 72 + cq * 16]);
  *(half8*)(ol + 8) = *(const half8*)(&ll[r * 72 + cq * 16 + 8]);
}

// ---------- pack heads transposed+split: whT[n][k] planes + bias ----------
__global__ __launch_bounds__(256) void k_packT(const float* __restrict__ wc_, const float* __restrict__ bc,
                                               const float* __restrict__ wr_, const float* __restrict__ br,
                                               f16* __restrict__ whT_hi, f16* __restrict__ whT_lo,
                                               float* __restrict__ bh) {
  uint32_t idx = blockIdx.x * 256u + threadIdx.x;
  if (idx < 512u * 1024u) {
    uint32_t n = idx >> 10, k = idx & 1023u;
    float v = 0.f;
    if (n < 81u) v = wc_[k * 81u + n];
    else if (n < 405u) v = wr_[k * 324u + (n - 81u)];
    f16 h, l; splitf16(v, h, l);
    whT_hi[idx] = h; whT_lo[idx] = l;
  } else if (idx < 512u * 1024u + 512u) {
    uint32_t n = idx - 512u * 1024u;
    float v = 0.f;
    if (n < 81u) v = bc[n];
    else if (n < 405u) v = br[n - 81u];
    bh[n] = v;
  }
}

// ---------- symmetric split-f16 GEMM: A[M][K], B-T [N][K] planes, 256x256, BK=32 ----------
// (FC2 and heads; passing since R4)
__global__ __launch_bounds__(512, 2) void k_gemm2(
    const f16* __restrict__ Ahi, const f16* __restrict__ Alo,
    const f16* __restrict__ Bhi, const f16* __restrict__ Blo,
    float* __restrict__ Cp, int K, int N, int Kc, int nMt, int nNt)
{
  __shared__ char sm[131072];
  const int t = threadIdx.x;
  const int lane = t & 63;
  const int wid = t >> 6;
  const int wr = wid >> 2;
  const int wc = wid & 3;
  const int rl = lane & 15;
  const int lq = lane >> 4;

  int bid = blockIdx.x;
  int low = bid & 7, qq = bid >> 3;
  int nt = qq % nNt;
  int chi = qq / nNt;
  int c = chi * 8 + low;
  int ks = c / nMt;
  int mt = c % nMt;
  const int brow = mt * 256;
  const int nbase = nt * 256;
  const int k0 = ks * Kc;
  const int nk = Kc >> 5;

  uint32_t aoffg[2], aldso[2];
#pragma unroll
  for (int i = 0; i < 2; ++i) {
    uint32_t idx = (uint32_t)t + 512u * i;
    uint32_t q2 = idx >> 2, s = idx & 3;
    uint32_t qh = q2 >> 6;
    uint32_t grh = (qh == 1u) ? 2u : (qh == 2u) ? 1u : qh;
    uint32_t gr = grh * 64u + (q2 & 63u);
    aoffg[i] = (uint32_t)(brow + gr) * (uint32_t)K + (s ^ ((q2 >> 1) & 3u)) * 8u;
    aldso[i] = idx * 16u;
  }
  uint32_t boffg[2], bldso[2];
#pragma unroll
  for (int i = 0; i < 2; ++i) {
    uint32_t idx = (uint32_t)t + 512u * i;
    uint32_t rB = idx >> 2, s = idx & 3;
    boffg[i] = (uint32_t)(nbase + rB) * (uint32_t)K + (s ^ ((rB >> 1) & 3u)) * 8u;
    bldso[i] = idx * 16u;
  }

  const uint32_t swzk = (uint32_t)(lq ^ ((rl >> 1) & 3)) * 16u;
  const uint32_t a_off_lane = (uint32_t)(rl * 64) + swzk;
  const uint32_t b_off_lane = (uint32_t)((wc * 16 + rl) * 64) + swzk;

  f32x4 zero4 = {0.f, 0.f, 0.f, 0.f};
  f32x4 acc[8][4];
#pragma unroll
  for (int m = 0; m < 8; ++m)
#pragma unroll
    for (int n = 0; n < 4; ++n) acc[m][n] = zero4;

#define PH0STAGE(LB, KB) do { \
    gload16(Bhi + boffg[0] + (KB), (LB) + 32768 + bldso[0]); \
    gload16(Blo + boffg[0] + (KB), (LB) + 49152 + bldso[0]); \
    gload16(Bhi + boffg[1] + (KB), (LB) + 32768 + bldso[1]); \
    gload16(Blo + boffg[1] + (KB), (LB) + 49152 + bldso[1]); \
    gload16(Ahi + aoffg[0] + (KB), (LB) + aldso[0]); \
    gload16(Alo + aoffg[0] + (KB), (LB) + 16384 + aldso[0]); \
  } while (0)

#define PH1STAGE(LB, KB) do { \
    gload16(Ahi + aoffg[1] + (KB), (LB) + aldso[1]); \
    gload16(Alo + aoffg[1] + (KB), (LB) + 16384 + aldso[1]); \
  } while (0)

#define COMPUTE_PHASE2(P) do { \
    half8 bh2[4], bl2[4]; \
    _Pragma("unroll") \
    for (int nf = 0; nf < 4; ++nf) { \
      bh2[nf] = *(const half8*)(lb + 32768 + nf * 4096 + b_off_lane); \
      bl2[nf] = *(const half8*)(lb + 49152 + nf * 4096 + b_off_lane); \
    } \
    __builtin_amdgcn_s_setprio(1); \
    _Pragma("unroll") \
    for (int mm = 0; mm < 4; ++mm) { \
      const char* ab = lb + (P) * 8192 + wr * 4096 + mm * 1024 + a_off_lane; \
      half8 ah = *(const half8*)(ab); \
      half8 al = *(const half8*)(ab + 16384); \
      _Pragma("unroll") \
      for (int nf = 0; nf < 4; ++nf) { \
        acc[(P)*4+mm][nf] = __builtin_amdgcn_mfma_f32_16x16x32_f16(ah, bh2[nf], acc[(P)*4+mm][nf], 0, 0, 0); \
        f32x4 tt = __builtin_amdgcn_mfma_f32_16x16x32_f16(ah, bl2[nf], zero4, 0, 0, 0); \
        tt = __builtin_amdgcn_mfma_f32_16x16x32_f16(al, bh2[nf], tt, 0, 0, 0); \
        acc[(P)*4+mm][nf] += tt * 4.8828125e-4f; \
      } \
    } \
    __builtin_amdgcn_s_setprio(0); \
  } while (0)

  PH0STAGE(sm, (uint32_t)k0);
  PH1STAGE(sm, (uint32_t)k0);

  int cur = 0;
  for (int kt = 0; kt < nk; ++kt) {
    int ktn = (kt + 1 < nk) ? kt + 1 : kt;
    uint32_t kbn = (uint32_t)(k0 + ktn * 32);
    const char* lb = sm + cur * 65536;
    char* lbn = sm + (cur ^ 1) * 65536;

    asm volatile("s_waitcnt vmcnt(2)" ::: "memory");
    __builtin_amdgcn_s_barrier();
    __builtin_amdgcn_sched_barrier(0);
    PH0STAGE(lbn, kbn);
    COMPUTE_PHASE2(0);

    asm volatile("s_waitcnt vmcnt(6)" ::: "memory");
    __builtin_amdgcn_s_barrier();
    __builtin_amdgcn_sched_barrier(0);
    PH1STAGE(lbn, kbn);
    COMPUTE_PHASE2(1);

    cur ^= 1;
  }

  float* Cs = Cp + (size_t)ks * ((size_t)512 * (uint32_t)N);
#pragma unroll
  for (int m = 0; m < 8; ++m) {
    int rg = brow + wr * 128 + m * 16 + lq * 4;
#pragma unroll
    for (int nf = 0; nf < 4; ++nf) {
      int cg = nbase + nf * 64 + wc * 16 + rl;
#pragma unroll
      for (int rr = 0; rr < 4; ++rr)
        Cs[(size_t)(rg + rr) * (uint32_t)N + cg] = acc[m][nf][rr];
    }
  }
#undef PH0STAGE
#undef PH1STAGE
#undef COMPUTE_PHASE2
}

// ---------- FC1 GEMM (R3-proven, 194us): A f16 planes; B f32 [K][N] in-loop split ----------
// LDS buf (64KB): [0,16K) Ahi [256][64B swz] | [16K,32K) Alo | [32K,64K) B as [half][32][512B swz]
__global__ __launch_bounds__(512, 2) void k_gemm3(
    const f16* __restrict__ Ahi, const f16* __restrict__ Alo,
    const float* __restrict__ B, float* __restrict__ Cp,
    int K, int N, int Kc, int nMt, int nNt)
{
  __shared__ char sm[131072];
  const int t = threadIdx.x;
  const int lane = t & 63;
  const int wid = t >> 6;
  const int wr = wid >> 2;
  const int wc = wid & 3;
  const int rl = lane & 15;
  const int lq = lane >> 4;

  int bid = blockIdx.x;
  int low = bid & 7, q = bid >> 3;
  int nt = q % nNt;
  int chi = q / nNt;
  int c = chi * 8 + low;
  int ks = c / nMt;
  int mt = c % nMt;
  const int brow = mt * 256;
  const int nbase = nt * 256;
  const int k0 = ks * Kc;
  const int nk = Kc >> 5;

  uint32_t aoffg[2], aldso[2];
#pragma unroll
  for (int i = 0; i < 2; ++i) {
    uint32_t idx = (uint32_t)t + 512u * i;
    uint32_t r = idx >> 2, s = idx & 3;
    uint32_t sz = s ^ ((r >> 1) & 3);
    aoffg[i] = (uint32_t)(brow + r) * (uint32_t)K + sz * 8u;
    aldso[i] = idx * 16u;
  }
  uint32_t boffg[2][2], bldso[2][2];
#pragma unroll
  for (int h = 0; h < 2; ++h)
#pragma unroll
    for (int i = 0; i < 2; ++i) {
      uint32_t idx = (uint32_t)t + 512u * i;
      uint32_t kr = idx >> 5, sg = idx & 31;
      uint32_t sgs = sg ^ (((kr >> 3) & 3) << 2);
      boffg[h][i] = kr * (uint32_t)N + (uint32_t)(nbase + h * 128) + sgs * 4u;
      bldso[h][i] = 32768u + (uint32_t)h * 16384u + idx * 16u;
    }

  const uint32_t a_off = (uint32_t)(wr * 8192 + rl * 64) + (uint32_t)((lq ^ ((rl >> 1) & 3)) * 16);
  const uint32_t b_lane = (uint32_t)((((wc ^ lq) & 3) * 16 + rl) * 4);

  f32x4 zero4 = {0.f, 0.f, 0.f, 0.f};
  f32x4 acc[8][4];
#pragma unroll
  for (int m = 0; m < 8; ++m)
#pragma unroll
    for (int n = 0; n < 4; ++n) acc[m][n] = zero4;

#define STAGE_A(LB, KB) do { \
    gload16(Ahi + aoffg[0] + (KB), (LB) + aldso[0]); \
    gload16(Alo + aoffg[0] + (KB), (LB) + 16384 + aldso[0]); \
    gload16(Ahi + aoffg[1] + (KB), (LB) + aldso[1]); \
    gload16(Alo + aoffg[1] + (KB), (LB) + 16384 + aldso[1]); \
  } while (0)

#define STAGE_B(LB, KB) do { \
    gload16(B + (size_t)(KB) * (uint32_t)N + boffg[0][0], (LB) + bldso[0][0]); \
    gload16(B + (size_t)(KB) * (uint32_t)N + boffg[0][1], (LB) + bldso[0][1]); \
    gload16(B + (size_t)(KB) * (uint32_t)N + boffg[1][0], (LB) + bldso[1][0]); \
    gload16(B + (size_t)(KB) * (uint32_t)N + boffg[1][1], (LB) + bldso[1][1]); \
  } while (0)

#define COMPUTE_PHASE(P) do { \
    half8 bhv[2], blv[2]; \
    _Pragma("unroll") \
    for (int x = 0; x < 2; ++x) { \
      const int nf = 2 * (P) + x; \
      const char* bb = lb + 32768 + (nf >> 1) * 16384 + (nf & 1) * 256 + b_lane; \
      _Pragma("unroll") \
      for (int jj = 0; jj < 8; jj += 2) { \
        float v0 = *(const float*)(bb + (lq * 8 + jj) * 512); \
        float v1 = *(const float*)(bb + (lq * 8 + jj + 1) * 512); \
        half2v hp = pkrtz(v0, v1); \
        f16 e0 = (fabsf(v0) >= 6.1035156e-5f) ? hp[0] : (f16)0; \
        f16 e1 = (fabsf(v1) >= 6.1035156e-5f) ? hp[1] : (f16)0; \
        half2v lp = pkrtz((v0 - (float)e0) * 2048.f, (v1 - (float)e1) * 2048.f); \
        bhv[x][jj] = e0; bhv[x][jj + 1] = e1; \
        blv[x][jj] = lp[0]; blv[x][jj + 1] = lp[1]; \
      } \
    } \
    __builtin_amdgcn_s_setprio(1); \
    _Pragma("unroll") \
    for (int m = 0; m < 8; ++m) { \
      half8 ah = *(const half8*)(lb + a_off + m * 1024); \
      half8 al = *(const half8*)(lb + 16384 + a_off + m * 1024); \
      _Pragma("unroll") \
      for (int x = 0; x < 2; ++x) { \
        const int nf = 2 * (P) + x; \
        acc[m][nf] = __builtin_amdgcn_mfma_f32_16x16x32_f16(ah, bhv[x], acc[m][nf], 0, 0, 0); \
        f32x4 tt = __builtin_amdgcn_mfma_f32_16x16x32_f16(ah, blv[x], zero4, 0, 0, 0); \
        tt = __builtin_amdgcn_mfma_f32_16x16x32_f16(al, bhv[x], tt, 0, 0, 0); \
        acc[m][nf] += tt * 4.8828125e-4f; \
      } \
    } \
    __builtin_amdgcn_s_setprio(0); \
  } while (0)

  STAGE_A(sm, (uint32_t)k0);
  STAGE_B(sm, (uint32_t)k0);

  int cur = 0;
  for (int kt = 0; kt < nk; ++kt) {
    int ktn = (kt + 1 < nk) ? kt + 1 : kt;
    uint32_t kbn = (uint32_t)(k0 + ktn * 32);
    const char* lb = sm + cur * 65536;
    char* lbn = sm + (cur ^ 1) * 65536;

    asm volatile("s_waitcnt vmcnt(2)" ::: "memory");
    __builtin_amdgcn_s_barrier();
    __builtin_amdgcn_sched_barrier(0);
    STAGE_A(lbn, kbn);
    COMPUTE_PHASE(0);

    asm volatile("s_waitcnt vmcnt(4)" ::: "memory");
    __builtin_amdgcn_s_barrier();
    __builtin_amdgcn_sched_barrier(0);
    STAGE_B(lbn, kbn);
    COMPUTE_PHASE(1);

    cur ^= 1;
  }

  float* Cs = Cp + (size_t)ks * ((size_t)512 * (uint32_t)N);
#pragma unroll
  for (int m = 0; m < 8; ++m) {
    int rg = brow + wr * 128 + m * 16 + lq * 4;
#pragma unroll
    for (int nf = 0; nf < 4; ++nf) {
      int cg = nbase + nf * 64 + wc * 16 + rl;
#pragma unroll
      for (int rr = 0; rr < 4; ++rr)
        Cs[(size_t)(rg + rr) * (uint32_t)N + cg] = acc[m][nf][rr];
    }
  }
#undef STAGE_A
#undef STAGE_B
#undef COMPUTE_PHASE
}

// ---------- reduce split-K partials (+bias, relu), float4 vectorized ----------
__global__ __launch_bounds__(256) void k_reduce(
    const float* __restrict__ parts, const float* __restrict__ bias,
    int nS, int MN4, int Ncols, int relu,
    float* __restrict__ outf, f16* __restrict__ ohi, f16* __restrict__ olo)
{
  uint32_t idx = blockIdx.x * 256u + threadIdx.x;
  if (idx >= (uint32_t)MN4) return;
  f32x4 s = *(const f32x4*)(bias + ((idx * 4u) % (uint32_t)Ncols));
  const f32x4* p4 = (const f32x4*)parts;
  for (int i = 0; i < nS; ++i) s += p4[(size_t)i * (uint32_t)MN4 + idx];
  if (relu) {
#pragma unroll
    for (int j = 0; j < 4; ++j) s[j] = fmaxf(s[j], 0.f);
  }
  if (outf) *(f32x4*)(outf + (size_t)idx * 4) = s;
  if (ohi) {
    half4v h, l;
#pragma unroll
    for (int j = 0; j < 4; ++j) { f16 hh, ll; splitf16(s[j], hh, ll); h[j] = hh; l[j] = ll; }
    *(half4v*)(ohi + (size_t)idx * 4) = h;
    *(half4v*)(olo + (size_t)idx * 4) = l;
  }
}

// ---------- fused tail: softmax/label/decode -> sort -> IoU mask -> NMS -> output ----------
__global__ __launch_bounds__(512) void k_tail(
    const float* __restrict__ ld, const float* __restrict__ prop,
    float* __restrict__ out)
{
  __shared__ float sbox[512][4];
  __shared__ float ssc[512];
  __shared__ int   slb[512];
  __shared__ unsigned long long keys[512];
  __shared__ unsigned long long maskw[512][8];   // 32 KB
  __shared__ unsigned long long kws[8];
  int t = threadIdx.x;

  // ---- phase 1: per-row softmax / argmax / box decode (mirrors np exactly) ----
  {
    const float* L = ld + (size_t)t * 512;
    float m = L[0];
    for (int j = 1; j < 81; ++j) m = fmaxf(m, L[j]);
    float sum = 0.f;
    for (int j = 0; j < 81; ++j) sum += expf(L[j] - m);
    float best = -1.f; int bj = 1;
    for (int j = 1; j < 81; ++j) {
      float p = expf(L[j] - m) / sum;
      if (p > best) { best = p; bj = j; }
    }
    float d0 = L[81 + bj * 4 + 0];
    float d1 = L[81 + bj * 4 + 1];
    float d2 = L[81 + bj * 4 + 2];
    float d3 = L[81 + bj * 4 + 3];
    float p0 = prop[t * 4 + 0], p1 = prop[t * 4 + 1], p2 = prop[t * 4 + 2], p3 = prop[t * 4 + 3];
    float w = p2 - p0, h = p3 - p1;
    float cx = p0 + 0.5f * w, cy = p1 + 0.5f * h;
    float px = cx + d0 * w, py = cy + d1 * h;
    float pw = w * expf(fminf(fmaxf(d2, -4.f), 4.f));
    float ph = h * expf(fminf(fmaxf(d3, -4.f), 4.f));
    sbox[t][0] = fminf(fmaxf(px - 0.5f * pw, 0.f), 799.f);
    sbox[t][1] = fminf(fmaxf(py - 0.5f * ph, 0.f), 799.f);
    sbox[t][2] = fminf(fmaxf(px + 0.5f * pw, 0.f), 799.f);
    sbox[t][3] = fminf(fmaxf(py + 0.5f * ph, 0.f), 799.f);
    ssc[t] = best;
    slb[t] = bj;
  }
  __syncthreads();

  // ---- phase 2: stable descending bitonic sort (key = ~scorebits : idx) ----
  {
    unsigned sb = __float_as_uint(ssc[t]);     // scores > 0 -> bits monotone
    keys[t] = ((unsigned long long)(0xFFFFFFFFu - sb) << 32) | (unsigned)t;
  }
  __syncthreads();
  for (int k = 2; k <= 512; k <<= 1) {
    for (int j = k >> 1; j > 0; j >>= 1) {
      int p = t ^ j;
      if (p > t) {
        unsigned long long a = keys[t], b = keys[p];
        bool asc = ((t & k) == 0);
        if (asc ? (a > b) : (a < b)) { keys[t] = b; keys[p] = a; }
      }
      __syncthreads();
    }
  }
  // gather sorted values through registers, then overwrite in place
  unsigned o = (unsigned)(keys[t] & 0xFFFFFFFFu);
  float g0 = sbox[o][0], g1 = sbox[o][1], g2 = sbox[o][2], g3 = sbox[o][3];
  float gs = ssc[o]; int gl = slb[o];
  __syncthreads();
  sbox[t][0] = g0; sbox[t][1] = g1; sbox[t][2] = g2; sbox[t][3] = g3;
  ssc[t] = gs; slb[t] = gl;
  __syncthreads();

  // ---- phase 3: suppression bitmask, thread t owns row t ----
  {
    float ax0 = sbox[t][0], ay0 = sbox[t][1], ax1 = sbox[t][2], ay1 = sbox[t][3];
    float aarea = fmaxf(ax1 - ax0, 0.f) * fmaxf(ay1 - ay0, 0.f);
    for (int w = 0; w < 8; ++w) {
      unsigned long long bits = 0ULL;
      for (int l = 0; l < 64; ++l) {
        int j = w * 64 + l;
        float bx0 = sbox[j][0], by0 = sbox[j][1], bx1 = sbox[j][2], by1 = sbox[j][3];
        float barea = fmaxf(bx1 - bx0, 0.f) * fmaxf(by1 - by0, 0.f);
        float ix0 = fmaxf(ax0, bx0), iy0 = fmaxf(ay0, by0);
        float ix1 = fminf(ax1, bx1), iy1 = fminf(ay1, by1);
        float inter = fmaxf(ix1 - ix0, 0.f) * fmaxf(iy1 - iy0, 0.f);
        float iou = inter / (aarea + barea - inter + 1e-6f);
        if ((iou > 0.5f) && (j > t)) bits |= (1ULL << l);
      }
      maskw[t][w] = bits;
    }
  }
  __syncthreads();

  // ---- phase 4: sequential NMS bit-sweep on wave 0 ----
  if (t < 64) {
    int lane = t;
    unsigned long long bal[8];
    for (int w = 0; w < 8; ++w) bal[w] = __ballot(ssc[w * 64 + lane] > 0.05f);
    unsigned long long keep = (lane < 8) ? bal[lane] : 0ULL;
    for (int i = 0; i < 512; ++i) {
      unsigned long long kw = __shfl(keep, i >> 6);
      if ((kw >> (i & 63)) & 1ULL) {
        unsigned long long mi = (lane < 8) ? maskw[i][lane] : 0ULL;
        keep &= ~mi;
      }
    }
    if (lane < 8) kws[lane] = keep;
  }
  __syncthreads();

  // ---- phase 5: output assembly (3584 floats, 7 per thread) ----
  for (int it = 0; it < 7; ++it) {
    int idx = t + it * 512;
    float val;
    if (idx < 2560) {
      int i = idx / 5, c2 = idx % 5;
      bool kb = (kws[i >> 6] >> (i & 63)) & 1ULL;
      val = kb ? (c2 < 4 ? sbox[i][c2] : ssc[i]) : 0.f;
    } else if (idx < 3072) {
      int i = idx - 2560;
      val = (float)slb[i];
    } else {
      int i = idx - 3072;
      val = ((kws[i >> 6] >> (i & 63)) & 1ULL) ? 1.f : 0.f;
    }
    out[idx] = val;
  }
}

// ---------- workspace layout ----------
static constexpr size_t SZ_X    = (size_t)NBOX * D1 * 2;            // 51,380,224
static constexpr size_t SZ_PART = (size_t)32 * 512 * 1024 * 4;      // 67,108,864
static constexpr size_t SZ_H    = (size_t)512 * 1024 * 2;
static constexpr size_t NP_XHI   = 0;
static constexpr size_t NP_XLO   = NP_XHI + SZ_X;
static constexpr size_t NP_PART  = NP_XLO + SZ_X;
static constexpr size_t NP_W2HIT = NP_PART + SZ_PART;
static constexpr size_t NP_W2LOT = NP_W2HIT + (size_t)1024 * 1024 * 2;
static constexpr size_t NP_WHHIT = NP_W2LOT + (size_t)1024 * 1024 * 2;
static constexpr size_t NP_WHLOT = NP_WHHIT + (size_t)512 * 1024 * 2;
static constexpr size_t NP_BH    = NP_WHLOT + (size_t)512 * 1024 * 2;
static constexpr size_t NP_H1HI  = NP_BH + 4096;
static constexpr size_t NP_H1LO  = NP_H1HI + SZ_H;
static constexpr size_t NP_H2HI  = NP_H1LO + SZ_H;
static constexpr size_t NP_H2LO  = NP_H2HI + SZ_H;
static constexpr size_t NP_LD    = NP_H2LO + SZ_H;
static constexpr size_t NP_END   = NP_LD + (size_t)512 * 512 * 4;

extern "C" void kernel_launch(void* const* d_in, const int* in_sizes, int n_in,
                              void* d_out, int out_size, void* d_ws, size_t ws_size,
                              hipStream_t stream)
{
  (void)in_sizes; (void)n_in;
  const float* feat = (const float*)d_in[0];
  const float* prop = (const float*)d_in[1];
  const float* w1   = (const float*)d_in[2];
  const float* b1   = (const float*)d_in[3];
  const float* w2   = (const float*)d_in[4];
  const float* b2   = (const float*)d_in[5];
  const float* wcls = (const float*)d_in[6];
  const float* bcls = (const float*)d_in[7];
  const float* wreg = (const float*)d_in[8];
  const float* breg = (const float*)d_in[9];
  float* out = (float*)d_out;
  char* W = (char*)d_ws;

  if (ws_size < NP_END) {                      // sentinel: workspace too small
    (void)hipMemsetAsync(out, 0x7f, (size_t)out_size * 4, stream);
    return;
  }

  f16*   xhi   = (f16*)(W + NP_XHI);
  f16*   xlo   = (f16*)(W + NP_XLO);
  float* parts = (float*)(W + NP_PART);
  f16*   w2hiT = (f16*)(W + NP_W2HIT);
  f16*   w2loT = (f16*)(W + NP_W2LOT);
  f16*   whHiT = (f16*)(W + NP_WHHIT);
  f16*   whLoT = (f16*)(W + NP_WHLOT);
  float* bhead = (float*)(W + NP_BH);
  f16*   h1hi  = (f16*)(W + NP_H1HI);
  f16*   h1lo  = (f16*)(W + NP_H1LO);
  f16*   h2hi  = (f16*)(W + NP_H2HI);
  f16*   h2lo  = (f16*)(W + NP_H2LO);
  float* ldbuf = (float*)(W + NP_LD);

  k_roi<<<50176, 256, 0, stream>>>(feat, prop, xhi, xlo);
  k_tsplit<<<dim3(1024 / 64, 1024 / 64), 256, 0, stream>>>(w2, w2hiT, w2loT, 1024, 1024);
  k_packT<<<2050, 256, 0, stream>>>(wcls, bcls, wreg, breg, whHiT, whLoT, bhead);

  // FC1: M=512 N=1024 K=50176, Kc=1568, grid 2*4*32=256, fused B-split (R3 structure)
  k_gemm3<<<256, 512, 0, stream>>>(xhi, xlo, w1, parts, D1, 1024, 1568, 2, 4);
  k_reduce<<<512, 256, 0, stream>>>(parts, b1, 32, 131072, 1024, 1, nullptr, h1hi, h1lo);

  // FC2: K=1024, Kc=32, grid 2*4*32=256
  k_gemm2<<<256, 512, 0, stream>>>(h1hi, h1lo, w2hiT, w2loT, parts, 1024, 1024, 32, 2, 4);
  k_reduce<<<512, 256, 0, stream>>>(parts, b2, 32, 131072, 1024, 1, nullptr, h2hi, h2lo);

  // heads: N=512, Kc=32, grid 2*2*32=128
  k_gemm2<<<128, 512, 0, stream>>>(h2hi, h2lo, whHiT, whLoT, parts, 1024, 512, 32, 2, 2);
  k_reduce<<<256, 256, 0, stream>>>(parts, bhead, 32, 65536, 512, 0, ldbuf, nullptr, nullptr);

  // fused post/sort/mask/NMS/output
  k_tail<<<1, 512, 0, stream>>>(ldbuf, prop, out);
}

// Round 10
// 422.980 us; speedup vs baseline: 3.1206x; 1.1425x over previous
//
#include <hip/hip_runtime.h>
#include <cstdint>

#define F_H 200
#define F_W 200
#define D1  50176
#define NBOX 512
#define NHID 1024

typedef _Float16 f16;
typedef _Float16 half8 __attribute__((ext_vector_type(8)));
typedef _Float16 half4v __attribute__((ext_vector_type(4)));
typedef _Float16 half2v __attribute__((ext_vector_type(2)));
typedef float    f32x4 __attribute__((ext_vector_type(4)));

// ---------- helpers ----------
__device__ __forceinline__ void gload16(const void* g, void* l) {
  __builtin_amdgcn_global_load_lds((const __attribute__((address_space(1))) void*)g,
                                   (__attribute__((address_space(3))) void*)l,
                                   16, 0, 0);
}

__device__ __forceinline__ half2v pkrtz(float a, float b) {
  return __builtin_bit_cast(half2v, __builtin_amdgcn_cvt_pkrtz(a, b));
}

// f32 -> f16 hi + f16 lo*2^-11 split; flush sub-normal hi so result is identical
// regardless of MFMA input-denormal behavior.
__device__ __forceinline__ void splitf16(float v, f16& h, f16& l) {
  f16 hh = (f16)v;
  float hf = (float)hh;
  if (fabsf(hf) < 6.1035156e-5f) hf = 0.f;
  h = (f16)hh;
  if (fabsf(hf) < 6.1035156e-5f) h = (f16)0.f;
  l = (f16)((v - hf) * 2048.f);
}

// ---------- ROI align + split (2 outputs per thread, 4B stores) ----------
__global__ __launch_bounds__(256) void k_roi(const float* __restrict__ feat,
                                             const float* __restrict__ prop,
                                             f16* __restrict__ xhi, f16* __restrict__ xlo) {
  uint32_t idx = blockIdx.x * 256u + threadIdx.x;
  uint32_t n = idx / 25088u;
  uint32_t rem = idx % 25088u;
  uint32_t c = rem / 98u;
  uint32_t r2 = rem % 98u;
  uint32_t i = r2 / 7u;
  uint32_t jp = r2 % 7u;
  float b0 = prop[n * 4 + 0] * 0.25f, b1 = prop[n * 4 + 1] * 0.25f;
  float b2 = prop[n * 4 + 2] * 0.25f, b3 = prop[n * 4 + 3] * 0.25f;
  float ty = ((float)i + 0.5f) * (1.0f / 14.0f);
  float yy = b1 + (b3 - b1) * ty;
  float y0f = floorf(yy);
  float fy = yy - y0f;
  int y0 = (int)y0f; y0 = y0 < 0 ? 0 : (y0 > F_H - 1 ? F_H - 1 : y0);
  int y1 = y0 + 1 > F_H - 1 ? F_H - 1 : y0 + 1;
  const float* fr0 = feat + (size_t)c * (F_H * F_W) + (size_t)y0 * F_W;
  const float* fr1 = feat + (size_t)c * (F_H * F_W) + (size_t)y1 * F_W;
  f16 hs[2], ls[2];
#pragma unroll
  for (int e = 0; e < 2; ++e) {
    uint32_t j = jp * 2u + (uint32_t)e;
    float tx = ((float)j + 0.5f) * (1.0f / 14.0f);
    float xx = b0 + (b2 - b0) * tx;
    float x0f = floorf(xx);
    float fx = xx - x0f;
    int x0 = (int)x0f; x0 = x0 < 0 ? 0 : (x0 > F_W - 1 ? F_W - 1 : x0);
    int x1 = x0 + 1 > F_W - 1 ? F_W - 1 : x0 + 1;
    float v00 = fr0[x0], v01 = fr0[x1], v10 = fr1[x0], v11 = fr1[x1];
    float v = (1.f - fx) * (1.f - fy) * v00 + fx * (1.f - fy) * v01 +
              (1.f - fx) * fy * v10 + fx * fy * v11;
    splitf16(v, hs[e], ls[e]);
  }
  uint32_t base = n * 50176u + c * 196u + i * 14u + jp * 2u;
  half2v hv; hv[0] = hs[0]; hv[1] = hs[1];
  half2v lv; lv[0] = ls[0]; lv[1] = ls[1];
  *(half2v*)(xhi + base) = hv;
  *(half2v*)(xlo + base) = lv;
}

// ---------- transpose + split: W[K][N] f32 -> hiT/loT [N][K] f16 (64x64 LDS tiles) ----------
__global__ __launch_bounds__(256) void k_tsplit(const float* __restrict__ W,
                                                f16* __restrict__ hiT, f16* __restrict__ loT,
                                                int Kdim, int Ndim) {
  __shared__ f16 lh[64 * 72];
  __shared__ f16 ll[64 * 72];
  int t = threadIdx.x;
  int k0 = blockIdx.x * 64, n0 = blockIdx.y * 64;
  int r = t >> 2, cq = t & 3;
  const float* src = W + (size_t)(k0 + r) * Ndim + n0 + cq * 16;
  f16 hv[16], lv[16];
#pragma unroll
  for (int e = 0; e < 4; ++e) {
    f32x4 v = *(const f32x4*)(src + e * 4);
#pragma unroll
    for (int x = 0; x < 4; ++x) splitf16(v[x], hv[e * 4 + x], lv[e * 4 + x]);
  }
#pragma unroll
  for (int j = 0; j < 16; ++j) {
    int n_l = cq * 16 + j;
    lh[n_l * 72 + r] = hv[j];
    ll[n_l * 72 + r] = lv[j];
  }
  __syncthreads();
  f16* oh = hiT + (size_t)(n0 + r) * Kdim + k0 + cq * 16;
  f16* ol = loT + (size_t)(n0 + r) * Kdim + k0 + cq * 16;
  *(half8*)(oh)     = *(const half8*)(&lh[r * 72 + cq * 16]);
  *(half8*)(oh + 8) = *(const half8*)(&lh[r * 72 + cq * 16 + 8]);
  *(half8*)(ol)     = *(const half8*)(&ll[r * 72 + cq * 16]);
  *(half8*)(ol + 8) = *(const half8*)(&ll[r * 72 + cq * 16 + 8]);
}

// ---------- pack heads transposed+split: whT[n][k] planes + bias ----------
__global__ __launch_bounds__(256) void k_packT(const float* __restrict__ wc_, const float* __restrict__ bc,
                                               const float* __restrict__ wr_, const float* __restrict__ br,
                                               f16* __restrict__ whT_hi, f16* __restrict__ whT_lo,
                                               float* __restrict__ bh) {
  uint32_t idx = blockIdx.x * 256u + threadIdx.x;
  if (idx < 512u * 1024u) {
    uint32_t n = idx >> 10, k = idx & 1023u;
    float v = 0.f;
    if (n < 81u) v = wc_[k * 81u + n];
    else if (n < 405u) v = wr_[k * 324u + (n - 81u)];
    f16 h, l; splitf16(v, h, l);
    whT_hi[idx] = h; whT_lo[idx] = l;
  } else if (idx < 512u * 1024u + 512u) {
    uint32_t n = idx - 512u * 1024u;
    float v = 0.f;
    if (n < 81u) v = bc[n];
    else if (n < 405u) v = br[n - 81u];
    bh[n] = v;
  }
}

// ---------- symmetric split-f16 GEMM: A[M][K], B-T [N][K] planes, 256x256, BK=32 ----------
// (FC2 and heads; passing since R4)
__global__ __launch_bounds__(512, 2) void k_gemm2(
    const f16* __restrict__ Ahi, const f16* __restrict__ Alo,
    const f16* __restrict__ Bhi, const f16* __restrict__ Blo,
    float* __restrict__ Cp, int K, int N, int Kc, int nMt, int nNt)
{
  __shared__ char sm[131072];
  const int t = threadIdx.x;
  const int lane = t & 63;
  const int wid = t >> 6;
  const int wr = wid >> 2;
  const int wc = wid & 3;
  const int rl = lane & 15;
  const int lq = lane >> 4;

  int bid = blockIdx.x;
  int low = bid & 7, qq = bid >> 3;
  int nt = qq % nNt;
  int chi = qq / nNt;
  int c = chi * 8 + low;
  int ks = c / nMt;
  int mt = c % nMt;
  const int brow = mt * 256;
  const int nbase = nt * 256;
  const int k0 = ks * Kc;
  const int nk = Kc >> 5;

  uint32_t aoffg[2], aldso[2];
#pragma unroll
  for (int i = 0; i < 2; ++i) {
    uint32_t idx = (uint32_t)t + 512u * i;
    uint32_t q2 = idx >> 2, s = idx & 3;
    uint32_t qh = q2 >> 6;
    uint32_t grh = (qh == 1u) ? 2u : (qh == 2u) ? 1u : qh;
    uint32_t gr = grh * 64u + (q2 & 63u);
    aoffg[i] = (uint32_t)(brow + gr) * (uint32_t)K + (s ^ ((q2 >> 1) & 3u)) * 8u;
    aldso[i] = idx * 16u;
  }
  uint32_t boffg[2], bldso[2];
#pragma unroll
  for (int i = 0; i < 2; ++i) {
    uint32_t idx = (uint32_t)t + 512u * i;
    uint32_t rB = idx >> 2, s = idx & 3;
    boffg[i] = (uint32_t)(nbase + rB) * (uint32_t)K + (s ^ ((rB >> 1) & 3u)) * 8u;
    bldso[i] = idx * 16u;
  }

  const uint32_t swzk = (uint32_t)(lq ^ ((rl >> 1) & 3)) * 16u;
  const uint32_t a_off_lane = (uint32_t)(rl * 64) + swzk;
  const uint32_t b_off_lane = (uint32_t)((wc * 16 + rl) * 64) + swzk;

  f32x4 zero4 = {0.f, 0.f, 0.f, 0.f};
  f32x4 acc[8][4];
#pragma unroll
  for (int m = 0; m < 8; ++m)
#pragma unroll
    for (int n = 0; n < 4; ++n) acc[m][n] = zero4;

#define PH0STAGE(LB, KB) do { \
    gload16(Bhi + boffg[0] + (KB), (LB) + 32768 + bldso[0]); \
    gload16(Blo + boffg[0] + (KB), (LB) + 49152 + bldso[0]); \
    gload16(Bhi + boffg[1] + (KB), (LB) + 32768 + bldso[1]); \
    gload16(Blo + boffg[1] + (KB), (LB) + 49152 + bldso[1]); \
    gload16(Ahi + aoffg[0] + (KB), (LB) + aldso[0]); \
    gload16(Alo + aoffg[0] + (KB), (LB) + 16384 + aldso[0]); \
  } while (0)

#define PH1STAGE(LB, KB) do { \
    gload16(Ahi + aoffg[1] + (KB), (LB) + aldso[1]); \
    gload16(Alo + aoffg[1] + (KB), (LB) + 16384 + aldso[1]); \
  } while (0)

#define COMPUTE_PHASE2(P) do { \
    half8 bh2[4], bl2[4]; \
    _Pragma("unroll") \
    for (int nf = 0; nf < 4; ++nf) { \
      bh2[nf] = *(const half8*)(lb + 32768 + nf * 4096 + b_off_lane); \
      bl2[nf] = *(const half8*)(lb + 49152 + nf * 4096 + b_off_lane); \
    } \
    __builtin_amdgcn_s_setprio(1); \
    _Pragma("unroll") \
    for (int mm = 0; mm < 4; ++mm) { \
      const char* ab = lb + (P) * 8192 + wr * 4096 + mm * 1024 + a_off_lane; \
      half8 ah = *(const half8*)(ab); \
      half8 al = *(const half8*)(ab + 16384); \
      _Pragma("unroll") \
      for (int nf = 0; nf < 4; ++nf) { \
        acc[(P)*4+mm][nf] = __builtin_amdgcn_mfma_f32_16x16x32_f16(ah, bh2[nf], acc[(P)*4+mm][nf], 0, 0, 0); \
        f32x4 tt = __builtin_amdgcn_mfma_f32_16x16x32_f16(ah, bl2[nf], zero4, 0, 0, 0); \
        tt = __builtin_amdgcn_mfma_f32_16x16x32_f16(al, bh2[nf], tt, 0, 0, 0); \
        acc[(P)*4+mm][nf] += tt * 4.8828125e-4f; \
      } \
    } \
    __builtin_amdgcn_s_setprio(0); \
  } while (0)

  PH0STAGE(sm, (uint32_t)k0);
  PH1STAGE(sm, (uint32_t)k0);

  int cur = 0;
  for (int kt = 0; kt < nk; ++kt) {
    int ktn = (kt + 1 < nk) ? kt + 1 : kt;
    uint32_t kbn = (uint32_t)(k0 + ktn * 32);
    const char* lb = sm + cur * 65536;
    char* lbn = sm + (cur ^ 1) * 65536;

    asm volatile("s_waitcnt vmcnt(2)" ::: "memory");
    __builtin_amdgcn_s_barrier();
    __builtin_amdgcn_sched_barrier(0);
    PH0STAGE(lbn, kbn);
    COMPUTE_PHASE2(0);

    asm volatile("s_waitcnt vmcnt(6)" ::: "memory");
    __builtin_amdgcn_s_barrier();
    __builtin_amdgcn_sched_barrier(0);
    PH1STAGE(lbn, kbn);
    COMPUTE_PHASE2(1);

    cur ^= 1;
  }

  float* Cs = Cp + (size_t)ks * ((size_t)512 * (uint32_t)N);
#pragma unroll
  for (int m = 0; m < 8; ++m) {
    int rg = brow + wr * 128 + m * 16 + lq * 4;
#pragma unroll
    for (int nf = 0; nf < 4; ++nf) {
      int cg = nbase + nf * 64 + wc * 16 + rl;
#pragma unroll
      for (int rr = 0; rr < 4; ++rr)
        Cs[(size_t)(rg + rr) * (uint32_t)N + cg] = acc[m][nf][rr];
    }
  }
#undef PH0STAGE
#undef PH1STAGE
#undef COMPUTE_PHASE2
}

// ---------- FC1 GEMM (R3-proven, 194us): A f16 planes; B f32 [K][N] in-loop split ----------
// LDS buf (64KB): [0,16K) Ahi [256][64B swz] | [16K,32K) Alo | [32K,64K) B as [half][32][512B swz]
__global__ __launch_bounds__(512, 2) void k_gemm3(
    const f16* __restrict__ Ahi, const f16* __restrict__ Alo,
    const float* __restrict__ B, float* __restrict__ Cp,
    int K, int N, int Kc, int nMt, int nNt)
{
  __shared__ char sm[131072];
  const int t = threadIdx.x;
  const int lane = t & 63;
  const int wid = t >> 6;
  const int wr = wid >> 2;
  const int wc = wid & 3;
  const int rl = lane & 15;
  const int lq = lane >> 4;

  int bid = blockIdx.x;
  int low = bid & 7, q = bid >> 3;
  int nt = q % nNt;
  int chi = q / nNt;
  int c = chi * 8 + low;
  int ks = c / nMt;
  int mt = c % nMt;
  const int brow = mt * 256;
  const int nbase = nt * 256;
  const int k0 = ks * Kc;
  const int nk = Kc >> 5;

  uint32_t aoffg[2], aldso[2];
#pragma unroll
  for (int i = 0; i < 2; ++i) {
    uint32_t idx = (uint32_t)t + 512u * i;
    uint32_t r = idx >> 2, s = idx & 3;
    uint32_t sz = s ^ ((r >> 1) & 3);
    aoffg[i] = (uint32_t)(brow + r) * (uint32_t)K + sz * 8u;
    aldso[i] = idx * 16u;
  }
  uint32_t boffg[2][2], bldso[2][2];
#pragma unroll
  for (int h = 0; h < 2; ++h)
#pragma unroll
    for (int i = 0; i < 2; ++i) {
      uint32_t idx = (uint32_t)t + 512u * i;
      uint32_t kr = idx >> 5, sg = idx & 31;
      uint32_t sgs = sg ^ (((kr >> 3) & 3) << 2);
      boffg[h][i] = kr * (uint32_t)N + (uint32_t)(nbase + h * 128) + sgs * 4u;
      bldso[h][i] = 32768u + (uint32_t)h * 16384u + idx * 16u;
    }

  const uint32_t a_off = (uint32_t)(wr * 8192 + rl * 64) + (uint32_t)((lq ^ ((rl >> 1) & 3)) * 16);
  const uint32_t b_lane = (uint32_t)((((wc ^ lq) & 3) * 16 + rl) * 4);

  f32x4 zero4 = {0.f, 0.f, 0.f, 0.f};
  f32x4 acc[8][4];
#pragma unroll
  for (int m = 0; m < 8; ++m)
#pragma unroll
    for (int n = 0; n < 4; ++n) acc[m][n] = zero4;

#define STAGE_A(LB, KB) do { \
    gload16(Ahi + aoffg[0] + (KB), (LB) + aldso[0]); \
    gload16(Alo + aoffg[0] + (KB), (LB) + 16384 + aldso[0]); \
    gload16(Ahi + aoffg[1] + (KB), (LB) + aldso[1]); \
    gload16(Alo + aoffg[1] + (KB), (LB) + 16384 + aldso[1]); \
  } while (0)

#define STAGE_B(LB, KB) do { \
    gload16(B + (size_t)(KB) * (uint32_t)N + boffg[0][0], (LB) + bldso[0][0]); \
    gload16(B + (size_t)(KB) * (uint32_t)N + boffg[0][1], (LB) + bldso[0][1]); \
    gload16(B + (size_t)(KB) * (uint32_t)N + boffg[1][0], (LB) + bldso[1][0]); \
    gload16(B + (size_t)(KB) * (uint32_t)N + boffg[1][1], (LB) + bldso[1][1]); \
  } while (0)

#define COMPUTE_PHASE(P) do { \
    half8 bhv[2], blv[2]; \
    _Pragma("unroll") \
    for (int x = 0; x < 2; ++x) { \
      const int nf = 2 * (P) + x; \
      const char* bb = lb + 32768 + (nf >> 1) * 16384 + (nf & 1) * 256 + b_lane; \
      _Pragma("unroll") \
      for (int jj = 0; jj < 8; jj += 2) { \
        float v0 = *(const float*)(bb + (lq * 8 + jj) * 512); \
        float v1 = *(const float*)(bb + (lq * 8 + jj + 1) * 512); \
        half2v hp = pkrtz(v0, v1); \
        f16 e0 = (fabsf(v0) >= 6.1035156e-5f) ? hp[0] : (f16)0; \
        f16 e1 = (fabsf(v1) >= 6.1035156e-5f) ? hp[1] : (f16)0; \
        half2v lp = pkrtz((v0 - (float)e0) * 2048.f, (v1 - (float)e1) * 2048.f); \
        bhv[x][jj] = e0; bhv[x][jj + 1] = e1; \
        blv[x][jj] = lp[0]; blv[x][jj + 1] = lp[1]; \
      } \
    } \
    __builtin_amdgcn_s_setprio(1); \
    _Pragma("unroll") \
    for (int m = 0; m < 8; ++m) { \
      half8 ah = *(const half8*)(lb + a_off + m * 1024); \
      half8 al = *(const half8*)(lb + 16384 + a_off + m * 1024); \
      _Pragma("unroll") \
      for (int x = 0; x < 2; ++x) { \
        const int nf = 2 * (P) + x; \
        acc[m][nf] = __builtin_amdgcn_mfma_f32_16x16x32_f16(ah, bhv[x], acc[m][nf], 0, 0, 0); \
        f32x4 tt = __builtin_amdgcn_mfma_f32_16x16x32_f16(ah, blv[x], zero4, 0, 0, 0); \
        tt = __builtin_amdgcn_mfma_f32_16x16x32_f16(al, bhv[x], tt, 0, 0, 0); \
        acc[m][nf] += tt * 4.8828125e-4f; \
      } \
    } \
    __builtin_amdgcn_s_setprio(0); \
  } while (0)

  STAGE_A(sm, (uint32_t)k0);
  STAGE_B(sm, (uint32_t)k0);

  int cur = 0;
  for (int kt = 0; kt < nk; ++kt) {
    int ktn = (kt + 1 < nk) ? kt + 1 : kt;
    uint32_t kbn = (uint32_t)(k0 + ktn * 32);
    const char* lb = sm + cur * 65536;
    char* lbn = sm + (cur ^ 1) * 65536;

    asm volatile("s_waitcnt vmcnt(2)" ::: "memory");
    __builtin_amdgcn_s_barrier();
    __builtin_amdgcn_sched_barrier(0);
    STAGE_A(lbn, kbn);
    COMPUTE_PHASE(0);

    asm volatile("s_waitcnt vmcnt(4)" ::: "memory");
    __builtin_amdgcn_s_barrier();
    __builtin_amdgcn_sched_barrier(0);
    STAGE_B(lbn, kbn);
    COMPUTE_PHASE(1);

    cur ^= 1;
  }

  float* Cs = Cp + (size_t)ks * ((size_t)512 * (uint32_t)N);
#pragma unroll
  for (int m = 0; m < 8; ++m) {
    int rg = brow + wr * 128 + m * 16 + lq * 4;
#pragma unroll
    for (int nf = 0; nf < 4; ++nf) {
      int cg = nbase + nf * 64 + wc * 16 + rl;
#pragma unroll
      for (int rr = 0; rr < 4; ++rr)
        Cs[(size_t)(rg + rr) * (uint32_t)N + cg] = acc[m][nf][rr];
    }
  }
#undef STAGE_A
#undef STAGE_B
#undef COMPUTE_PHASE
}

// ---------- reduce split-K partials (+bias, relu), float4 vectorized ----------
__global__ __launch_bounds__(256) void k_reduce(
    const float* __restrict__ parts, const float* __restrict__ bias,
    int nS, int MN4, int Ncols, int relu,
    float* __restrict__ outf, f16* __restrict__ ohi, f16* __restrict__ olo)
{
  uint32_t idx = blockIdx.x * 256u + threadIdx.x;
  if (idx >= (uint32_t)MN4) return;
  f32x4 s = *(const f32x4*)(bias + ((idx * 4u) % (uint32_t)Ncols));
  const f32x4* p4 = (const f32x4*)parts;
  for (int i = 0; i < nS; ++i) s += p4[(size_t)i * (uint32_t)MN4 + idx];
  if (relu) {
#pragma unroll
    for (int j = 0; j < 4; ++j) s[j] = fmaxf(s[j], 0.f);
  }
  if (outf) *(f32x4*)(outf + (size_t)idx * 4) = s;
  if (ohi) {
    half4v h, l;
#pragma unroll
    for (int j = 0; j < 4; ++j) { f16 hh, ll; splitf16(s[j], hh, ll); h[j] = hh; l[j] = ll; }
    *(half4v*)(ohi + (size_t)idx * 4) = h;
    *(half4v*)(olo + (size_t)idx * 4) = l;
  }
}

// ---------- per-row softmax / label / score / box decode ----------
__global__ __launch_bounds__(256) void k_post(
    const float* __restrict__ ld, const float* __restrict__ prop,
    float* __restrict__ boxes, float* __restrict__ scores, int* __restrict__ labels)
{
  int n = blockIdx.x * 256 + threadIdx.x;
  if (n >= NBOX) return;
  const float* L = ld + (size_t)n * 512;
  float m = L[0];
  for (int j = 1; j < 81; ++j) m = fmaxf(m, L[j]);
  float sum = 0.f;
  for (int j = 0; j < 81; ++j) sum += expf(L[j] - m);
  float best = -1.f; int bj = 1;
  for (int j = 1; j < 81; ++j) {
    float p = expf(L[j] - m) / sum;
    if (p > best) { best = p; bj = j; }
  }
  float d0 = L[81 + bj * 4 + 0];
  float d1 = L[81 + bj * 4 + 1];
  float d2 = L[81 + bj * 4 + 2];
  float d3 = L[81 + bj * 4 + 3];
  float p0 = prop[n * 4 + 0], p1 = prop[n * 4 + 1], p2 = prop[n * 4 + 2], p3 = prop[n * 4 + 3];
  float w = p2 - p0, h = p3 - p1;
  float cx = p0 + 0.5f * w, cy = p1 + 0.5f * h;
  float px = cx + d0 * w, py = cy + d1 * h;
  float pw = w * expf(fminf(fmaxf(d2, -4.f), 4.f));
  float ph = h * expf(fminf(fmaxf(d3, -4.f), 4.f));
  float bx0 = px - 0.5f * pw, by0 = py - 0.5f * ph;
  float bx1 = px + 0.5f * pw, by1 = py + 0.5f * ph;
  boxes[n * 4 + 0] = fminf(fmaxf(bx0, 0.f), 799.f);
  boxes[n * 4 + 1] = fminf(fmaxf(by0, 0.f), 799.f);
  boxes[n * 4 + 2] = fminf(fmaxf(bx1, 0.f), 799.f);
  boxes[n * 4 + 3] = fminf(fmaxf(by1, 0.f), 799.f);
  scores[n] = best;
  labels[n] = bj;
}

// ---------- stable descending bitonic sort (key = ~scorebits : idx) ----------
__global__ __launch_bounds__(512) void k_sort(
    const float* __restrict__ scores, const float* __restrict__ boxes, const int* __restrict__ labels,
    float* __restrict__ bs, float* __restrict__ ss, int* __restrict__ ls)
{
  __shared__ unsigned long long keys[512];
  int t = threadIdx.x;
  unsigned sb = __float_as_uint(scores[t]);
  keys[t] = ((unsigned long long)(0xFFFFFFFFu - sb) << 32) | (unsigned)t;
  __syncthreads();
  for (int k = 2; k <= 512; k <<= 1) {
    for (int j = k >> 1; j > 0; j >>= 1) {
      int p = t ^ j;
      if (p > t) {
        unsigned long long a = keys[t], b = keys[p];
        bool asc = ((t & k) == 0);
        if (asc ? (a > b) : (a < b)) { keys[t] = b; keys[p] = a; }
      }
      __syncthreads();
    }
  }
  unsigned o = (unsigned)(keys[t] & 0xFFFFFFFFu);
  ss[t] = scores[o];
  ls[t] = labels[o];
  bs[t * 4 + 0] = boxes[o * 4 + 0];
  bs[t * 4 + 1] = boxes[o * 4 + 1];
  bs[t * 4 + 2] = boxes[o * 4 + 2];
  bs[t * 4 + 3] = boxes[o * 4 + 3];
}

// ---------- IoU suppression bitmask ----------
__global__ __launch_bounds__(64) void k_mask(const float* __restrict__ bs,
                                             unsigned long long* __restrict__ mask) {
  int i = blockIdx.x;
  int lane = threadIdx.x;
  float ax0 = bs[i * 4], ay0 = bs[i * 4 + 1], ax1 = bs[i * 4 + 2], ay1 = bs[i * 4 + 3];
  float aarea = fmaxf(ax1 - ax0, 0.f) * fmaxf(ay1 - ay0, 0.f);
  for (int w = 0; w < 8; ++w) {
    int j = w * 64 + lane;
    float bx0 = bs[j * 4], by0 = bs[j * 4 + 1], bx1 = bs[j * 4 + 2], by1 = bs[j * 4 + 3];
    float barea = fmaxf(bx1 - bx0, 0.f) * fmaxf(by1 - by0, 0.f);
    float ix0 = fmaxf(ax0, bx0), iy0 = fmaxf(ay0, by0);
    float ix1 = fminf(ax1, bx1), iy1 = fminf(ay1, by1);
    float inter = fmaxf(ix1 - ix0, 0.f) * fmaxf(iy1 - iy0, 0.f);
    float iou = inter / (aarea + barea - inter + 1e-6f);
    bool cond = (iou > 0.5f) && (j > i);
    unsigned long long b = __ballot(cond);
    if (lane == 0) mask[i * 8 + w] = b;
  }
}

// ---------- sequential NMS + output assembly ----------
__global__ __launch_bounds__(64) void k_nms(const unsigned long long* __restrict__ mask,
                                            const float* __restrict__ ss,
                                            const float* __restrict__ bs,
                                            const int* __restrict__ ls,
                                            float* __restrict__ out) {
  int lane = threadIdx.x;
  unsigned long long bal[8];
  for (int w = 0; w < 8; ++w) bal[w] = __ballot(ss[w * 64 + lane] > 0.05f);
  unsigned long long keep = (lane < 8) ? bal[lane] : 0ULL;
  for (int i = 0; i < 512; ++i) {
    unsigned long long kw = __shfl(keep, i >> 6);
    if ((kw >> (i & 63)) & 1ULL) {
      unsigned long long mi = (lane < 8) ? mask[i * 8 + lane] : 0ULL;
      keep &= ~mi;
    }
  }
  __shared__ unsigned long long kws[8];
  if (lane < 8) kws[lane] = keep;
  __syncthreads();
  for (int it = 0; it < 56; ++it) {
    int idx = lane + it * 64;
    float val;
    if (idx < 2560) {
      int i = idx / 5, c2 = idx % 5;
      bool kb = (kws[i >> 6] >> (i & 63)) & 1ULL;
      val = kb ? (c2 < 4 ? bs[i * 4 + c2] : ss[i]) : 0.f;
    } else if (idx < 3072) {
      int i = idx - 2560;
      val = (float)ls[i];
    } else {
      int i = idx - 3072;
      val = ((kws[i >> 6] >> (i & 63)) & 1ULL) ? 1.f : 0.f;
    }
    out[idx] = val;
  }
}

// ---------- workspace layout ----------
static constexpr size_t SZ_X    = (size_t)NBOX * D1 * 2;            // 51,380,224
static constexpr size_t SZ_PART = (size_t)32 * 512 * 1024 * 4;      // 67,108,864
static constexpr size_t SZ_H    = (size_t)512 * 1024 * 2;
static constexpr size_t NP_XHI   = 0;
static constexpr size_t NP_XLO   = NP_XHI + SZ_X;
static constexpr size_t NP_PART  = NP_XLO + SZ_X;
static constexpr size_t NP_W2HIT = NP_PART + SZ_PART;
static constexpr size_t NP_W2LOT = NP_W2HIT + (size_t)1024 * 1024 * 2;
static constexpr size_t NP_WHHIT = NP_W2LOT + (size_t)1024 * 1024 * 2;
static constexpr size_t NP_WHLOT = NP_WHHIT + (size_t)512 * 1024 * 2;
static constexpr size_t NP_BH    = NP_WHLOT + (size_t)512 * 1024 * 2;
static constexpr size_t NP_H1HI  = NP_BH + 4096;
static constexpr size_t NP_H1LO  = NP_H1HI + SZ_H;
static constexpr size_t NP_H2HI  = NP_H1LO + SZ_H;
static constexpr size_t NP_H2LO  = NP_H2HI + SZ_H;
static constexpr size_t NP_LD    = NP_H2LO + SZ_H;
static constexpr size_t NP_BOX   = NP_LD + (size_t)512 * 512 * 4;
static constexpr size_t NP_SC    = NP_BOX + 512 * 4 * 4;
static constexpr size_t NP_LB    = NP_SC + 4096;
static constexpr size_t NP_BS    = NP_LB + 4096;
static constexpr size_t NP_SS    = NP_BS + 512 * 4 * 4;
static constexpr size_t NP_LS    = NP_SS + 4096;
static constexpr size_t NP_MASK  = NP_LS + 4096;
static constexpr size_t NP_END   = NP_MASK + (size_t)512 * 8 * 8;

extern "C" void kernel_launch(void* const* d_in, const int* in_sizes, int n_in,
                              void* d_out, int out_size, void* d_ws, size_t ws_size,
                              hipStream_t stream)
{
  (void)in_sizes; (void)n_in;
  const float* feat = (const float*)d_in[0];
  const float* prop = (const float*)d_in[1];
  const float* w1   = (const float*)d_in[2];
  const float* b1   = (const float*)d_in[3];
  const float* w2   = (const float*)d_in[4];
  const float* b2   = (const float*)d_in[5];
  const float* wcls = (const float*)d_in[6];
  const float* bcls = (const float*)d_in[7];
  const float* wreg = (const float*)d_in[8];
  const float* breg = (const float*)d_in[9];
  float* out = (float*)d_out;
  char* W = (char*)d_ws;

  if (ws_size < NP_END) {                      // sentinel: workspace too small
    (void)hipMemsetAsync(out, 0x7f, (size_t)out_size * 4, stream);
    return;
  }

  f16*   xhi   = (f16*)(W + NP_XHI);
  f16*   xlo   = (f16*)(W + NP_XLO);
  float* parts = (float*)(W + NP_PART);
  f16*   w2hiT = (f16*)(W + NP_W2HIT);
  f16*   w2loT = (f16*)(W + NP_W2LOT);
  f16*   whHiT = (f16*)(W + NP_WHHIT);
  f16*   whLoT = (f16*)(W + NP_WHLOT);
  float* bhead = (float*)(W + NP_BH);
  f16*   h1hi  = (f16*)(W + NP_H1HI);
  f16*   h1lo  = (f16*)(W + NP_H1LO);
  f16*   h2hi  = (f16*)(W + NP_H2HI);
  f16*   h2lo  = (f16*)(W + NP_H2LO);
  float* ldbuf = (float*)(W + NP_LD);
  float* boxes = (float*)(W + NP_BOX);
  float* scores= (float*)(W + NP_SC);
  int*   labels= (int*)(W + NP_LB);
  float* bsrt  = (float*)(W + NP_BS);
  float* ssrt  = (float*)(W + NP_SS);
  int*   lsrt  = (int*)(W + NP_LS);
  unsigned long long* maskb = (unsigned long long*)(W + NP_MASK);

  k_roi<<<50176, 256, 0, stream>>>(feat, prop, xhi, xlo);
  k_tsplit<<<dim3(1024 / 64, 1024 / 64), 256, 0, stream>>>(w2, w2hiT, w2loT, 1024, 1024);
  k_packT<<<2050, 256, 0, stream>>>(wcls, bcls, wreg, breg, whHiT, whLoT, bhead);

  // FC1: M=512 N=1024 K=50176, Kc=1568, grid 2*4*32=256, fused B-split (R3 structure)
  k_gemm3<<<256, 512, 0, stream>>>(xhi, xlo, w1, parts, D1, 1024, 1568, 2, 4);
  k_reduce<<<512, 256, 0, stream>>>(parts, b1, 32, 131072, 1024, 1, nullptr, h1hi, h1lo);

  // FC2: K=1024, Kc=32, grid 2*4*32=256
  k_gemm2<<<256, 512, 0, stream>>>(h1hi, h1lo, w2hiT, w2loT, parts, 1024, 1024, 32, 2, 4);
  k_reduce<<<512, 256, 0, stream>>>(parts, b2, 32, 131072, 1024, 1, nullptr, h2hi, h2lo);

  // heads: N=512, Kc=32, grid 2*2*32=128
  k_gemm2<<<128, 512, 0, stream>>>(h2hi, h2lo, whHiT, whLoT, parts, 1024, 512, 32, 2, 2);
  k_reduce<<<256, 256, 0, stream>>>(parts, bhead, 32, 65536, 512, 0, ldbuf, nullptr, nullptr);

  k_post<<<2, 256, 0, stream>>>(ldbuf, prop, boxes, scores, labels);
  k_sort<<<1, 512, 0, stream>>>(scores, boxes, labels, bsrt, ssrt, lsrt);
  k_mask<<<512, 64, 0, stream>>>(bsrt, maskb);
  k_nms<<<1, 64, 0, stream>>>(maskb, ssrt, bsrt, lsrt, out);
}